// Round 12
// baseline (1705.386 us; speedup 1.0000x reference)
//
#include <hip/hip_runtime.h>
#include <hip/hip_bf16.h>
#include <math.h>

#define HIDN 256
#define GATES 1024
#define LLEN 128
#define WLEN 48
#define SNUM 5
#define PLEN 32
#define EMBD 256

typedef _Float16 f16;
typedef _Float16 h2_t __attribute__((ext_vector_type(2)));
typedef short short8_t __attribute__((ext_vector_type(8)));
typedef float f32x4 __attribute__((ext_vector_type(4)));

__device__ __forceinline__ float sigf(float x){ return 1.0f/(1.0f+expf(-x)); }

__device__ __forceinline__ unsigned short f2bf(float f){
  unsigned int x = __builtin_bit_cast(unsigned int, f);
  x += 0x7fffu + ((x >> 16) & 1u);
  return (unsigned short)(x >> 16);
}
__device__ __forceinline__ float bf2f(unsigned short u){
  unsigned int x = ((unsigned int)u) << 16;
  return __builtin_bit_cast(float, x);
}

__device__ __forceinline__ float fd2(unsigned int w, unsigned int h, float acc){
  h2_t wa = __builtin_bit_cast(h2_t, w);
  h2_t hb = __builtin_bit_cast(h2_t, h);
#if defined(__has_builtin)
#if __has_builtin(__builtin_amdgcn_fdot2)
  return __builtin_amdgcn_fdot2(wa, hb, acc, false);
#else
  return acc + (float)wa[0]*(float)hb[0] + (float)wa[1]*(float)hb[1];
#endif
#else
  return acc + (float)wa[0]*(float)hb[0] + (float)wa[1]*(float)hb[1];
#endif
}
__device__ __forceinline__ float dot8(uint4 w, uint4 h, float acc){
  acc = fd2(w.x, h.x, acc);
  acc = fd2(w.y, h.y, acc);
  acc = fd2(w.z, h.z, acc);
  acc = fd2(w.w, h.w, acc);
  return acc;
}

// =======================================================================
// fp32 tiled GEMM (Wp / Ws final projections)
// =======================================================================
template<bool GATHER, bool BIAS, bool RELU, bool SPLIT>
__global__ __launch_bounds__(256) void gemm_abt64_k(
  const float* __restrict__ A, const float* __restrict__ A2,
  const float* __restrict__ Bm, const float* __restrict__ bias,
  float* __restrict__ C, const int* __restrict__ gidx,
  int K, int N, int ostride)
{
  __shared__ float As[32][68];
  __shared__ float Bs[32][68];
  const int tid = threadIdx.x;
  const int m0 = blockIdx.x*64, n0 = blockIdx.y*64;
  const int tx = tid & 15, ty = tid >> 4;
  const int lr = tid >> 3;
  const int lc = (tid & 7) * 4;
  float acc[4][4] = {};
  for (int k0 = 0; k0 < K; k0 += 32){
    #pragma unroll
    for (int hf = 0; hf < 2; ++hf){
      const int r = lr + hf*32;
      int am = m0 + r;
      if (GATHER) am = gidx[am];
      const float* asrc;
      if (SPLIT){
        if (k0 < 256) asrc = A  + (size_t)am*256 + k0 + lc;
        else          asrc = A2 + (size_t)am*256 + (k0-256) + lc;
      } else {
        asrc = A + (size_t)am*K + k0 + lc;
      }
      float4 av = *reinterpret_cast<const float4*>(asrc);
      float4 bv = *reinterpret_cast<const float4*>(Bm + (size_t)(n0+r)*K + k0 + lc);
      As[lc+0][r]=av.x; As[lc+1][r]=av.y; As[lc+2][r]=av.z; As[lc+3][r]=av.w;
      Bs[lc+0][r]=bv.x; Bs[lc+1][r]=bv.y; Bs[lc+2][r]=bv.z; Bs[lc+3][r]=bv.w;
    }
    __syncthreads();
    #pragma unroll
    for (int kk = 0; kk < 32; ++kk){
      const float4 a = *reinterpret_cast<const float4*>(&As[kk][ty*4]);
      const float4 b = *reinterpret_cast<const float4*>(&Bs[kk][tx*4]);
      acc[0][0] += a.x*b.x; acc[0][1] += a.x*b.y; acc[0][2] += a.x*b.z; acc[0][3] += a.x*b.w;
      acc[1][0] += a.y*b.x; acc[1][1] += a.y*b.y; acc[1][2] += a.y*b.z; acc[1][3] += a.y*b.w;
      acc[2][0] += a.z*b.x; acc[2][1] += a.z*b.y; acc[2][2] += a.z*b.z; acc[2][3] += a.z*b.w;
      acc[3][0] += a.w*b.x; acc[3][1] += a.w*b.y; acc[3][2] += a.w*b.z; acc[3][3] += a.w*b.w;
    }
    __syncthreads();
  }
  float4 bb;
  if (BIAS) bb = *reinterpret_cast<const float4*>(bias + n0 + tx*4);
  else      { bb.x=0.f; bb.y=0.f; bb.z=0.f; bb.w=0.f; }
  #pragma unroll
  for (int i = 0; i < 4; ++i){
    float4 o;
    o.x = acc[i][0]+bb.x; o.y = acc[i][1]+bb.y; o.z = acc[i][2]+bb.z; o.w = acc[i][3]+bb.w;
    if (RELU){ o.x=fmaxf(o.x,0.f); o.y=fmaxf(o.y,0.f); o.z=fmaxf(o.z,0.f); o.w=fmaxf(o.w,0.f); }
    *reinterpret_cast<float4*>(C + (size_t)(m0+ty*4+i)*ostride + n0 + tx*4) = o;
  }
}

// converters
__global__ __launch_bounds__(256) void cvt2_k(
  const float* __restrict__ a, const float* __restrict__ b,
  unsigned short* __restrict__ oa, unsigned short* __restrict__ ob, int n)
{
  for (int i = blockIdx.x*256 + threadIdx.x; i < n; i += gridDim.x*256){
    oa[i] = f2bf(a[i]);
    ob[i] = f2bf(b[i]);
  }
}
__global__ __launch_bounds__(256) void cvt1_k(
  const float* __restrict__ a, unsigned short* __restrict__ o, int n)
{
  for (int i = blockIdx.x*256 + threadIdx.x; i < n; i += gridDim.x*256)
    o[i] = f2bf(a[i]);
}
__global__ __launch_bounds__(256) void cvt_w16_k(
  const float* __restrict__ a, const float* __restrict__ b,
  f16* __restrict__ oa, f16* __restrict__ ob)
{
  const int i = blockIdx.x*256 + threadIdx.x;
  oa[i] = (f16)a[i];
  ob[i] = (f16)b[i];
}

// gather-index remap: gidx2[t*1024 + u] = tok[u*48 + t]
__global__ __launch_bounds__(256) void remap_k(const int* __restrict__ tok, int* __restrict__ gidx2){
  const int idx = blockIdx.x*256 + threadIdx.x;
  const int t = idx >> 10, u = idx & 1023;
  gidx2[idx] = tok[u*WLEN + t];
}

// =======================================================================
// bf16 MFMA GEMM (xwc/xws paths): C(Mx1024) = A(Mx256) @ W(1024x256)^T + b
// =======================================================================
template<int AMODE>
__global__ __launch_bounds__(256) void mmabt_k(
  const void* __restrict__ Asrc, const unsigned short* __restrict__ Wb,
  const float* __restrict__ bias, const int* __restrict__ gidx,
  float* __restrict__ Cout)
{
  __shared__ char As[32768];
  const int tid = threadIdx.x;
  const int w = tid >> 6, l = tid & 63;
  const int lr = l & 15, lg = l >> 4;
  const int m0 = blockIdx.x*64, n0 = blockIdx.y*64;
  #pragma unroll
  for (int q = 0; q < 8; ++q){
    const int ck = tid*8 + q;
    const int rl = ck >> 5, o16 = ck & 31;
    int row = m0 + rl;
    if (AMODE == 1) row = gidx[row];
    char* dst = As + rl*512 + ((o16*16) ^ ((rl & 7) << 4));
    *reinterpret_cast<short8_t*>(dst) = *reinterpret_cast<const short8_t*>(
        (const unsigned short*)Asrc + (size_t)row*256 + o16*8);
  }
  __syncthreads();
  short8_t a[8];
  #pragma unroll
  for (int ks = 0; ks < 8; ++ks){
    const int rl = w*16 + lr;
    a[ks] = *reinterpret_cast<const short8_t*>(As + rl*512 + ((ks*64 + lg*16) ^ ((rl & 7) << 4)));
  }
  #pragma unroll
  for (int nt = 0; nt < 4; ++nt){
    f32x4 acc = f32x4{0,0,0,0};
    const int n = n0 + nt*16 + lr;
    #pragma unroll
    for (int ks = 0; ks < 8; ++ks){
      short8_t b = *reinterpret_cast<const short8_t*>(Wb + (size_t)n*256 + ks*32 + lg*8);
      acc = __builtin_amdgcn_mfma_f32_16x16x32_bf16(a[ks], b, acc, 0, 0, 0);
    }
    const float bn = bias[n];
    #pragma unroll
    for (int r = 0; r < 4; ++r){
      const int m = m0 + w*16 + lg*4 + r;
      Cout[(size_t)m*1024 + n] = acc[r] + bn;
    }
  }
}

// =======================================================================
// X-GEMM with packed gate-interleaved output
// =======================================================================
__global__ __launch_bounds__(256) void xgemm4_k(
  const float* __restrict__ emb, const unsigned short* __restrict__ Wb,
  const float* __restrict__ bias, const int* __restrict__ gidx,
  unsigned short* __restrict__ Xp)
{
  __shared__ char As[32768];
  const int tid = threadIdx.x;
  const int w = tid >> 6, l = tid & 63;
  const int lr = l & 15, lg = l >> 4;
  const int m0 = blockIdx.x*64;
  const int j0 = blockIdx.y*64;
  #pragma unroll
  for (int q = 0; q < 8; ++q){
    const int ck = tid*8 + q;
    const int rl = ck >> 5, o16 = ck & 31;
    const int row = gidx[m0 + rl];
    const float* src = emb + (size_t)row*256 + o16*8;
    float4 f0 = *reinterpret_cast<const float4*>(src);
    float4 f1 = *reinterpret_cast<const float4*>(src + 4);
    union { short8_t s; unsigned short u[8]; } pk;
    pk.u[0]=f2bf(f0.x); pk.u[1]=f2bf(f0.y); pk.u[2]=f2bf(f0.z); pk.u[3]=f2bf(f0.w);
    pk.u[4]=f2bf(f1.x); pk.u[5]=f2bf(f1.y); pk.u[6]=f2bf(f1.z); pk.u[7]=f2bf(f1.w);
    *reinterpret_cast<short8_t*>(As + rl*512 + ((o16*16) ^ ((rl & 7) << 4))) = pk.s;
  }
  __syncthreads();
  const int jw = j0 + w*16;
  float bs_g[4];
  #pragma unroll
  for (int g = 0; g < 4; ++g) bs_g[g] = bias[g*256 + jw + lr];
  #pragma unroll
  for (int mt = 0; mt < 4; ++mt){
    short8_t a[8];
    const int rl = mt*16 + lr;
    #pragma unroll
    for (int ks = 0; ks < 8; ++ks)
      a[ks] = *reinterpret_cast<const short8_t*>(
          As + rl*512 + ((ks*64 + lg*16) ^ ((rl & 7) << 4)));
    f32x4 acc[4];
    #pragma unroll
    for (int g = 0; g < 4; ++g){
      acc[g] = f32x4{0,0,0,0};
      const unsigned short* wb = Wb + (size_t)(g*256 + jw + lr)*256 + lg*8;
      #pragma unroll
      for (int ks = 0; ks < 8; ++ks){
        short8_t b = *reinterpret_cast<const short8_t*>(wb + ks*32);
        acc[g] = __builtin_amdgcn_mfma_f32_16x16x32_bf16(a[ks], b, acc[g], 0, 0, 0);
      }
    }
    #pragma unroll
    for (int r = 0; r < 4; ++r){
      const int m = m0 + mt*16 + lg*4 + r;
      unsigned long long pk =
          (unsigned long long)f2bf(acc[0][r] + bs_g[0])
        | ((unsigned long long)f2bf(acc[1][r] + bs_g[1]) << 16)
        | ((unsigned long long)f2bf(acc[2][r] + bs_g[2]) << 32)
        | ((unsigned long long)f2bf(acc[3][r] + bs_g[3]) << 48);
      *reinterpret_cast<unsigned long long*>(Xp + (size_t)m*1024 + (jw + lr)*4) = pk;
    }
  }
}

// =======================================================================
// Word LSTM v6: 64 blocks x 512 threads (8 waves -> the PROVEN 128-VGPR
// grant tier; r3/r6 evidence). Wave w owns 32 j-cols x all 4 gates via
// 2 jt-subtiles (per-jt update keeps acc at 16 regs). i-gate resident in
// 64 VGPRs; o-gate in 128 KB LDS (XOR-swizzled); f+g streamed from L2
// (t-invariant addrs laundered). h bf16 dbuf in LDS. Demand ~122 <= 128.
// =======================================================================
__global__ __launch_bounds__(512, 1) void word6_k(
  const unsigned short* __restrict__ Xp,   // [t*1024+seq][j*4+gate] bf16
  const unsigned short* __restrict__ Wb,   // uWhh bf16 [1024][256]
  unsigned short* __restrict__ woutb)      // [seq][t][256] bf16
{
  extern __shared__ char smem[];
  const int tid = threadIdx.x;
  const int w = tid >> 6, l = tid & 63;
  const int lr = l & 15, lg = l >> 4;
  const int S0 = blockIdx.x * 16;
  const int jb = w * 32;
  char* olds = smem + w*16384;             // wave-local o-gate: 32 rows x 512 B
  char* hb0  = smem + 131072;
  char* hb1  = smem + 139264;

  // zero both h buffers (16 KB = 512 threads x 2 x 16 B)
  reinterpret_cast<uint4*>(hb0)[tid] = uint4{0,0,0,0};
  reinterpret_cast<uint4*>(hb0)[512 + tid] = uint4{0,0,0,0};

  // stage o-gate slice: rows 768 + jb + 0..31 (16 KB per wave)
  #pragma unroll
  for (int q = 0; q < 16; ++q){
    const int ck = l*16 + q;               // 0..1023 chunks of 16B
    const int rl = ck >> 5, o16 = ck & 31;
    short8_t v = *reinterpret_cast<const short8_t*>(
        Wb + (size_t)(768 + jb + rl)*256 + o16*8);
    *reinterpret_cast<short8_t*>(olds + rl*512 + ((o16*16) ^ ((rl & 7) << 4))) = v;
  }
  // i-gate B-frags resident (2 jt x 8 ks = 16 short8 = 64 VGPRs)
  short8_t wi[2][8];
  #pragma unroll
  for (int jt = 0; jt < 2; ++jt)
    #pragma unroll
    for (int ks = 0; ks < 8; ++ks)
      wi[jt][ks] = *reinterpret_cast<const short8_t*>(
          Wb + (size_t)(jb + jt*16 + lr)*256 + ks*32 + lg*8);
  const unsigned short* fbase = Wb + (size_t)(256 + jb + lr)*256 + lg*8;
  const unsigned short* gbase = Wb + (size_t)(512 + jb + lr)*256 + lg*8;
  float c_reg[2][4] = {};
  __syncthreads();

  for (int t = 0; t < WLEN; ++t){
    const char* hr = (t & 1) ? hb1 : hb0;
    char* hw = (t & 1) ? hb0 : hb1;
    const unsigned short* pf = fbase;
    const unsigned short* pg = gbase;
    asm volatile("" : "+v"(pf), "+v"(pg));   // re-stream f,g each step
    #pragma unroll
    for (int jt = 0; jt < 2; ++jt){
      const int j = jb + jt*16 + lr;
      // prefetch X for this jt (issues before MFMA chain)
      unsigned long long xv[4];
      #pragma unroll
      for (int r = 0; r < 4; ++r)
        xv[r] = *reinterpret_cast<const unsigned long long*>(
            Xp + ((size_t)t*1024 + (S0 + lg*4 + r))*1024 + j*4);
      f32x4 aI = f32x4{0,0,0,0}, aF = f32x4{0,0,0,0};
      f32x4 aG = f32x4{0,0,0,0}, aO = f32x4{0,0,0,0};
      #pragma unroll
      for (int ks = 0; ks < 8; ++ks){
        short8_t a = *reinterpret_cast<const short8_t*>(
            hr + lr*512 + ((ks*64 + lg*16) ^ ((lr & 7) << 4)));
        short8_t bf = *reinterpret_cast<const short8_t*>(pf + (size_t)(jt*16)*256 + ks*32);
        short8_t bg = *reinterpret_cast<const short8_t*>(pg + (size_t)(jt*16)*256 + ks*32);
        const int ro = jt*16 + lr;
        short8_t bo = *reinterpret_cast<const short8_t*>(
            olds + ro*512 + ((ks*64 + lg*16) ^ ((ro & 7) << 4)));
        aI = __builtin_amdgcn_mfma_f32_16x16x32_bf16(a, wi[jt][ks], aI, 0, 0, 0);
        aF = __builtin_amdgcn_mfma_f32_16x16x32_bf16(a, bf, aF, 0, 0, 0);
        aG = __builtin_amdgcn_mfma_f32_16x16x32_bf16(a, bg, aG, 0, 0, 0);
        aO = __builtin_amdgcn_mfma_f32_16x16x32_bf16(a, bo, aO, 0, 0, 0);
      }
      #pragma unroll
      for (int r = 0; r < 4; ++r){
        const int s = lg*4 + r;
        float gi = aI[r] + bf2f((unsigned short)(xv[r]));
        float gf = aF[r] + bf2f((unsigned short)(xv[r] >> 16));
        float gg = aG[r] + bf2f((unsigned short)(xv[r] >> 32));
        float go = aO[r] + bf2f((unsigned short)(xv[r] >> 48));
        float cc = sigf(gf)*c_reg[jt][r] + sigf(gi)*tanhf(gg);
        c_reg[jt][r] = cc;
        float hh = sigf(go)*tanhf(cc);
        unsigned short h16 = f2bf(hh);
        woutb[((size_t)(S0+s)*WLEN + t)*256 + j] = h16;
        *reinterpret_cast<unsigned short*>(hw + s*512 + ((j*2) ^ ((s & 7) << 4))) = h16;
      }
    }
    __syncthreads();
  }
}

// =======================================================================
// conv + sess recurrent LSTM v4: 512 threads (128-VGPR tier), 2 gate-rows
// per thread. Weights f16 three-way: k0..95 in 96 VGPRs, k96..159 in
// 128 KB LDS, k160..255 streamed from L2 per step (issued FIRST, 4 acc
// chains so loads pipeline). blocks 0..7: conv T=128; 8..39: sess T=32.
// Demand ~122 <= 128.
// =======================================================================
__global__ __launch_bounds__(512, 1) void recur4_k(
  const float* __restrict__ xwc, const f16* __restrict__ w16c, float* __restrict__ convb,
  const float* __restrict__ xws, const f16* __restrict__ w16s, float* __restrict__ soutb)
{
  const float* xw; const f16* w16; float* out; int seq, T;
  if (blockIdx.x < 8){ seq = blockIdx.x;     T = 128; xw = xwc; w16 = w16c; out = convb; }
  else               { seq = blockIdx.x - 8; T = 32;  xw = xws; w16 = w16s; out = soutb; }

  extern __shared__ char smem[];
  uint4* w_lds  = (uint4*)smem;                    // [8][1024] 16B = 128 KB (k 96..159)
  float* g_s    = (float*)(smem + 131072);         // 4 KB
  f16*   h_half = (f16*)(smem + 131072 + 4096);    // 512 B
  const uint4* h4 = (const uint4*)h_half;          // 32 chunks of 8 f16

  const int tid = threadIdx.x;
  const int n0 = tid, n1 = tid + 512;
  // LDS part: k 96..159 for both rows
  #pragma unroll
  for (int cth = 0; cth < 8; ++cth){
    w_lds[cth*1024 + n0] = *reinterpret_cast<const uint4*>(w16 + (size_t)n0*256 + 96 + cth*8);
    w_lds[cth*1024 + n1] = *reinterpret_cast<const uint4*>(w16 + (size_t)n1*256 + 96 + cth*8);
  }
  // register part: k 0..95 (12 uint4 per row = 96 VGPRs total)
  uint4 wr[24];
  #pragma unroll
  for (int k = 0; k < 12; ++k){
    wr[k]    = *reinterpret_cast<const uint4*>(w16 + (size_t)n0*256 + k*8);
    wr[12+k] = *reinterpret_cast<const uint4*>(w16 + (size_t)n1*256 + k*8);
  }
  const f16* sb0 = w16 + (size_t)n0*256 + 160;     // stream part k 160..255
  const f16* sb1 = w16 + (size_t)n1*256 + 160;
  if (tid < 32) reinterpret_cast<uint4*>(h_half)[tid] = uint4{0,0,0,0};
  float c_reg = 0.f;
  __syncthreads();

  float xn0 = xw[(size_t)(seq*T)*GATES + n0];
  float xn1 = xw[(size_t)(seq*T)*GATES + n1];
  for (int t = 0; t < T; ++t){
    const float acc0 = xn0, acc1 = xn1;
    if (t + 1 < T){
      xn0 = xw[(size_t)(seq*T + t + 1)*GATES + n0];
      xn1 = xw[(size_t)(seq*T + t + 1)*GATES + n1];
    }
    const f16* ps0 = sb0;
    const f16* ps1 = sb1;
    asm volatile("" : "+v"(ps0), "+v"(ps1));       // re-stream each step
    // streamed part FIRST (k 160..255 -> h chunks 20..31), 4 chains
    float s0 = 0.f, s1 = 0.f, s2 = 0.f, s3 = 0.f;
    #pragma unroll
    for (int k = 0; k < 12; k += 2){
      uint4 u0 = *reinterpret_cast<const uint4*>(ps0 + k*8);
      uint4 u1 = *reinterpret_cast<const uint4*>(ps0 + (k+1)*8);
      uint4 v0 = *reinterpret_cast<const uint4*>(ps1 + k*8);
      uint4 v1 = *reinterpret_cast<const uint4*>(ps1 + (k+1)*8);
      const uint4 h0 = h4[20+k], h1 = h4[21+k];
      s0 = dot8(u0, h0, s0);
      s1 = dot8(u1, h1, s1);
      s2 = dot8(v0, h0, s2);
      s3 = dot8(v1, h1, s3);
    }
    // register part (k 0..95 -> chunks 0..11)
    float a0 = 0.f, a1 = 0.f, b0 = 0.f, b1 = 0.f;
    #pragma unroll
    for (int k = 0; k < 12; k += 2){
      const uint4 h0 = h4[k], h1 = h4[k+1];
      a0 = dot8(wr[k],    h0, a0);
      a1 = dot8(wr[k+1],  h1, a1);
      b0 = dot8(wr[12+k], h0, b0);
      b1 = dot8(wr[13+k], h1, b1);
    }
    // LDS part (chunks 12..19)
    #pragma unroll
    for (int cth = 0; cth < 8; cth += 2){
      const uint4 h0 = h4[12+cth], h1 = h4[13+cth];
      a0 = dot8(w_lds[cth*1024 + n0],     h0, a0);
      a1 = dot8(w_lds[(cth+1)*1024 + n0], h1, a1);
      b0 = dot8(w_lds[cth*1024 + n1],     h0, b0);
      b1 = dot8(w_lds[(cth+1)*1024 + n1], h1, b1);
    }
    g_s[n0] = acc0 + (a0+a1) + (s0+s1);
    g_s[n1] = acc1 + (b0+b1) + (s2+s3);
    __syncthreads();
    if (tid < HIDN){
      const int j = tid;
      float gi = g_s[j], gf = g_s[HIDN+j], gg = g_s[2*HIDN+j], go = g_s[3*HIDN+j];
      float cc = sigf(gf)*c_reg + sigf(gi)*tanhf(gg);
      c_reg = cc;
      float hh = sigf(go)*tanhf(cc);
      h_half[j] = (f16)hh;
      out[(size_t)(seq*T + t)*HIDN + j] = hh;
    }
    __syncthreads();
  }
}

// =======================================================================
// attention logits via bf16 MFMA + fused tanh/ws2 contraction
// =======================================================================
__global__ __launch_bounds__(256) void attlog_k(
  const unsigned short* __restrict__ woutb, const unsigned short* __restrict__ ws1b,
  const float* __restrict__ ws2, float* __restrict__ logits)
{
  const int tid = threadIdx.x;
  const int w = tid >> 6, l = tid & 63;
  const int lr = l & 15, lg = l >> 4;
  const int m0 = blockIdx.x*64;
  short8_t a[8];
  #pragma unroll
  for (int ks = 0; ks < 8; ++ks){
    const int m = m0 + w*16 + lr;
    a[ks] = *reinterpret_cast<const short8_t*>(woutb + (size_t)m*256 + ks*32 + lg*8);
  }
  float part[4] = {0.f, 0.f, 0.f, 0.f};
  #pragma unroll
  for (int nt = 0; nt < 16; ++nt){
    f32x4 acc = f32x4{0,0,0,0};
    const int n = nt*16 + lr;
    #pragma unroll
    for (int ks = 0; ks < 8; ++ks){
      short8_t b = *reinterpret_cast<const short8_t*>(ws1b + (size_t)n*256 + ks*32 + lg*8);
      acc = __builtin_amdgcn_mfma_f32_16x16x32_bf16(a[ks], b, acc, 0, 0, 0);
    }
    const float w2 = ws2[n];
    #pragma unroll
    for (int r = 0; r < 4; ++r) part[r] += w2 * tanhf(acc[r]);
  }
  #pragma unroll
  for (int r = 0; r < 4; ++r){
    float p = part[r];
    p += __shfl_xor(p, 1, 64);
    p += __shfl_xor(p, 2, 64);
    p += __shfl_xor(p, 4, 64);
    p += __shfl_xor(p, 8, 64);
    if (lr == 0) logits[m0 + w*16 + lg*4 + r] = p;
  }
}

// masked softmax over W + weighted sum -> att fp32 + attb bf16
__global__ __launch_bounds__(256) void att_softmax_k(
  const unsigned short* __restrict__ woutb, const float* __restrict__ logits,
  const int* __restrict__ tok, float* __restrict__ att, unsigned short* __restrict__ attb)
{
  __shared__ float e[WLEN];
  __shared__ float den_s;
  const int n = blockIdx.x, j = threadIdx.x;
  if (j < WLEN){
    float lgt = logits[n*WLEN + j];
    if (tok[n*WLEN + j] == 0) lgt -= 10000.0f;
    e[j] = lgt;
  }
  __syncthreads();
  if (j == 0){
    float mx = -1e30f;
    for (int ww = 0; ww < WLEN; ++ww) mx = fmaxf(mx, e[ww]);
    float den = 0.f;
    for (int ww = 0; ww < WLEN; ++ww){ float ee = expf(e[ww]-mx); e[ww] = ee; den += ee; }
    den_s = den;
  }
  __syncthreads();
  const float inv = 1.0f/den_s;
  float a = 0.f;
  for (int ww = 0; ww < WLEN; ++ww)
    a += e[ww]*bf2f(woutb[((size_t)n*WLEN + ww)*HIDN + j]);
  a *= inv;
  att[(size_t)n*HIDN + j] = a;
  attb[(size_t)n*HIDN + j] = f2bf(a);
}

// =======================================================================
// Fallback word LSTM (fp32, only if workspace too small for X)
// =======================================================================
__global__ __launch_bounds__(256) void word_gates_k(
    const int* __restrict__ tok, const float* __restrict__ emb,
    const float* __restrict__ Wih, const float* __restrict__ Whh,
    const float* __restrict__ bias, const float* __restrict__ hbuf,
    float* __restrict__ G, int t)
{
  __shared__ float As[32][68];
  __shared__ float Bs[32][68];
  const int tid = threadIdx.x;
  const int m0 = blockIdx.x*64, n0 = blockIdx.y*64;
  const int tx = tid & 15, ty = tid >> 4;
  const int lr = tid >> 3;
  const int lc = (tid & 7) * 4;
  float acc[4][4] = {};
  for (int kt = 0; kt < 16; ++kt){
    const int k0 = (kt & 7)*32;
    const bool xp = (kt < 8);
    #pragma unroll
    for (int hf = 0; hf < 2; ++hf){
      const int r = lr + hf*32;
      float4 av, bv;
      if (xp){
        const int token = tok[(m0+r)*WLEN + t];
        av = *reinterpret_cast<const float4*>(emb + (size_t)token*EMBD + k0 + lc);
      } else {
        av = *reinterpret_cast<const float4*>(hbuf + (size_t)(m0+r)*HIDN + k0 + lc);
      }
      const float* bptr = (xp ? Wih : Whh) + (size_t)(n0+r)*HIDN + k0 + lc;
      bv = *reinterpret_cast<const float4*>(bptr);
      As[lc+0][r]=av.x; As[lc+1][r]=av.y; As[lc+2][r]=av.z; As[lc+3][r]=av.w;
      Bs[lc+0][r]=bv.x; Bs[lc+1][r]=bv.y; Bs[lc+2][r]=bv.z; Bs[lc+3][r]=bv.w;
    }
    __syncthreads();
    #pragma unroll
    for (int kk = 0; kk < 32; ++kk){
      const float4 a = *reinterpret_cast<const float4*>(&As[kk][ty*4]);
      const float4 b = *reinterpret_cast<const float4*>(&Bs[kk][tx*4]);
      acc[0][0] += a.x*b.x; acc[0][1] += a.x*b.y; acc[0][2] += a.x*b.z; acc[0][3] += a.x*b.w;
      acc[1][0] += a.y*b.x; acc[1][1] += a.y*b.y; acc[1][2] += a.y*b.z; acc[1][3] += a.y*b.w;
      acc[2][0] += a.z*b.x; acc[2][1] += a.z*b.y; acc[2][2] += a.z*b.z; acc[2][3] += a.z*b.w;
      acc[3][0] += a.w*b.x; acc[3][1] += a.w*b.y; acc[3][2] += a.w*b.z; acc[3][3] += a.w*b.w;
    }
    __syncthreads();
  }
  const float4 bb = *reinterpret_cast<const float4*>(bias + n0 + tx*4);
  #pragma unroll
  for (int i = 0; i < 4; ++i){
    float4 o;
    o.x = acc[i][0]+bb.x; o.y = acc[i][1]+bb.y; o.z = acc[i][2]+bb.z; o.w = acc[i][3]+bb.w;
    *reinterpret_cast<float4*>(G + (size_t)(m0+ty*4+i)*GATES + n0 + tx*4) = o;
  }
}

__global__ __launch_bounds__(256) void word_update_k(
  const float* __restrict__ G, float* __restrict__ h, float* __restrict__ c,
  unsigned short* __restrict__ woutb, int t)
{
  int idx = blockIdx.x*256 + threadIdx.x;
  int m = idx >> 8, j = idx & 255;
  const float* g = G + (size_t)m*GATES;
  float gi = g[j], gf = g[HIDN+j], gg = g[2*HIDN+j], go = g[3*HIDN+j];
  float cc = c[idx];
  cc = sigf(gf)*cc + sigf(gi)*tanhf(gg);
  float hh = sigf(go)*tanhf(cc);
  c[idx] = cc; h[idx] = hh;
  woutb[(size_t)m*WLEN*HIDN + (size_t)t*HIDN + j] = f2bf(hh);
}

// =======================================================================
// Parallel state "scan" prep
// =======================================================================
__global__ __launch_bounds__(256) void scan_prep_k(
  const float* __restrict__ sess_out, const float* __restrict__ conv_out,
  const int* __restrict__ stm, float* __restrict__ state, float* __restrict__ onec)
{
  const int bl = blockIdx.x;
  const int b = bl >> 7, l = bl & 127;
  const int j = threadIdx.x;
  float ones = 0.f;
  #pragma unroll
  for (int s = 1; s < SNUM; ++s){
    const int sv = stm[(size_t)bl*SNUM + s];
    float vg = 0.f;
    if (sv > 0){
      int p = sv - 1; if (p > PLEN-1) p = PLEN-1;
      vg = sess_out[((size_t)(b*4 + (s-1))*PLEN + p)*HIDN + j];
    }
    float v = vg;
    if (sv == -1){
      v = 0.f;
      if (l > 0){
        const int pv = stm[(size_t)(bl-1)*SNUM + s];
        if (pv > 0){
          int p2 = pv - 1; if (p2 > PLEN-1) p2 = PLEN-1;
          v = sess_out[((size_t)(b*4 + (s-1))*PLEN + p2)*HIDN + j];
        }
      }
    }
    if (sv != 0) ones += v;
    state[((size_t)bl*SNUM + s)*HIDN + j] = vg;
  }
  onec[(size_t)bl*(2*HIDN) + j] = ones * 0.25f;
  const int lp = (l == 0) ? 0 : (l-1);
  onec[(size_t)bl*(2*HIDN) + HIDN + j] = conv_out[((size_t)(b*LLEN + lp))*HIDN + j];
}

// =======================================================================
// final scores + log_softmax
// =======================================================================
__global__ __launch_bounds__(256) void scores_k(
  const float* __restrict__ state, const float* __restrict__ up, float* __restrict__ out)
{
  const int n = blockIdx.x, j = threadIdx.x;
  __shared__ float red[SNUM][4];
  const float u = up[(size_t)n*HIDN + j];
  const int lane = j & 63, wid = j >> 6;
  #pragma unroll
  for (int s = 0; s < SNUM; ++s){
    float p = state[((size_t)n*SNUM + s)*HIDN + j]*u;
    for (int off = 32; off; off >>= 1) p += __shfl_down(p, off, 64);
    if (lane == 0) red[s][wid] = p;
  }
  __syncthreads();
  if (j == 0){
    float sc[SNUM]; float mx = -1e30f;
    #pragma unroll
    for (int s = 0; s < SNUM; ++s){
      sc[s] = red[s][0]+red[s][1]+red[s][2]+red[s][3];
      mx = fmaxf(mx, sc[s]);
    }
    float den = 0.f;
    #pragma unroll
    for (int s = 0; s < SNUM; ++s) den += expf(sc[s]-mx);
    const float ls = logf(den);
    #pragma unroll
    for (int s = 0; s < SNUM; ++s) out[(size_t)n*SNUM + s] = sc[s]-mx-ls;
  }
}

// ---------------- workspace layout (float offsets) ----------------
static const size_t OFF_G     = 0;                        // fallback
static const size_t OFF_H     = OFF_G     + 1048576;
static const size_t OFF_C     = OFF_H     + 262144;
static const size_t OFF_ATT   = OFF_C     + 262144;
static const size_t OFF_ATTB  = OFF_ATT   + 262144;       // bf16 att
static const size_t OFF_XWC   = OFF_ATTB  + 131072;
static const size_t OFF_XWS   = OFF_XWC   + 1048576;
static const size_t OFF_CONV  = OFF_XWS   + 1048576;
static const size_t OFF_SOUT  = OFF_CONV  + 262144;
static const size_t OFF_STATE = OFF_SOUT  + 262144;
static const size_t OFF_ONEC  = OFF_STATE + 1310720;
static const size_t OFF_UP    = OFF_ONEC  + 524288;
static const size_t OFF_LOG   = OFF_UP    + 262144;
static const size_t OFF_GIDX2 = OFF_LOG   + 49152;
static const size_t OFF_UWHHB = OFF_GIDX2 + 49152;        // bf16 uWhh
static const size_t OFF_WIHB  = OFF_UWHHB + 131072;       // bf16 uWih
static const size_t OFF_WS1B  = OFF_WIHB  + 131072;       // bf16 ws1
static const size_t OFF_CWIHB = OFF_WS1B  + 32768;        // bf16 cWih
static const size_t OFF_SWIHB = OFF_CWIHB + 131072;       // bf16 sWih
static const size_t OFF_W16C  = OFF_SWIHB + 131072;       // f16 cWhh
static const size_t OFF_W16S  = OFF_W16C  + 131072;       // f16 sWhh
static const size_t OFF_WOUTB = OFF_W16S  + 131072;       // bf16 wout
static const size_t OFF_X     = OFF_WOUTB + 6291456;      // bf16 X (gate-interleaved)
static const size_t NEED_X_FLOATS = OFF_X + (size_t)49152*512;

static const size_t WORD_LDS_BYTES  = 131072 + 16384;         // 147456
static const size_t RECUR_LDS_BYTES = 131072 + 4096 + 512;    // 135680

extern "C" void kernel_launch(void* const* d_in, const int* in_sizes, int n_in,
                              void* d_out, int out_size, void* d_ws, size_t ws_size,
                              hipStream_t stream)
{
  const int*   tok   = (const int*)  d_in[0];
  const int*   perm  = (const int*)  d_in[2];
  const int*   stm   = (const int*)  d_in[3];
  const float* emb   = (const float*)d_in[5];
  const float* uWih  = (const float*)d_in[6];
  const float* uWhh  = (const float*)d_in[7];
  const float* ub    = (const float*)d_in[8];
  const float* ws1   = (const float*)d_in[9];
  const float* ws2   = (const float*)d_in[10];
  const float* cWih  = (const float*)d_in[11];
  const float* cWhh  = (const float*)d_in[12];
  const float* cb    = (const float*)d_in[13];
  const float* sWih  = (const float*)d_in[14];
  const float* sWhh  = (const float*)d_in[15];
  const float* sb    = (const float*)d_in[16];
  const float* Wp    = (const float*)d_in[17];
  const float* bp    = (const float*)d_in[18];
  const float* Ws    = (const float*)d_in[19];
  const float* bs    = (const float*)d_in[20];

  float* wsf    = (float*)d_ws;
  float* G      = wsf + OFF_G;
  float* h      = wsf + OFF_H;
  float* c      = wsf + OFF_C;
  float* att    = wsf + OFF_ATT;
  float* xwc    = wsf + OFF_XWC;
  float* xws    = wsf + OFF_XWS;
  float* convb  = wsf + OFF_CONV;
  float* soutb  = wsf + OFF_SOUT;
  float* statem = wsf + OFF_STATE;
  float* onec   = wsf + OFF_ONEC;
  float* upb    = wsf + OFF_UP;
  float* logits = wsf + OFF_LOG;
  int*   gidx2  = (int*)(wsf + OFF_GIDX2);
  unsigned short* attb  = (unsigned short*)(wsf + OFF_ATTB);
  unsigned short* uwhhb = (unsigned short*)(wsf + OFF_UWHHB);
  unsigned short* wihb  = (unsigned short*)(wsf + OFF_WIHB);
  unsigned short* ws1b  = (unsigned short*)(wsf + OFF_WS1B);
  unsigned short* cwihb = (unsigned short*)(wsf + OFF_CWIHB);
  unsigned short* swihb = (unsigned short*)(wsf + OFF_SWIHB);
  f16*   w16c   = (f16*)(wsf + OFF_W16C);
  f16*   w16s   = (f16*)(wsf + OFF_W16S);
  unsigned short* woutb = (unsigned short*)(wsf + OFF_WOUTB);
  unsigned short* X16   = (unsigned short*)(wsf + OFF_X);

  const bool useX = ws_size >= NEED_X_FLOATS*sizeof(float);

  hipFuncSetAttribute(reinterpret_cast<const void*>(word6_k),
                      hipFuncAttributeMaxDynamicSharedMemorySize, (int)WORD_LDS_BYTES);
  hipFuncSetAttribute(reinterpret_cast<const void*>(recur4_k),
                      hipFuncAttributeMaxDynamicSharedMemorySize, (int)RECUR_LDS_BYTES);

  // weight conversions
  cvt2_k<<<256, 256, 0, stream>>>(uWhh, uWih, uwhhb, wihb, 262144);
  cvt2_k<<<256, 256, 0, stream>>>(cWih, sWih, cwihb, swihb, 262144);
  cvt_w16_k<<<1024, 256, 0, stream>>>(cWhh, sWhh, w16c, w16s);
  cvt1_k<<<64, 256, 0, stream>>>(ws1, ws1b, 65536);

  // ---- word LSTM ----
  if (useX){
    remap_k<<<192, 256, 0, stream>>>(tok, gidx2);
    xgemm4_k<<<dim3(768,4), 256, 0, stream>>>(emb, wihb, ub, gidx2, X16);
    word6_k<<<64, 512, WORD_LDS_BYTES, stream>>>(X16, uwhhb, woutb);
  } else {
    hipMemsetAsync(h, 0, 2*262144*sizeof(float), stream);
    for (int t = 0; t < WLEN; ++t){
      word_gates_k<<<dim3(16,16), 256, 0, stream>>>(tok, emb, uWih, uWhh, ub, h, G, t);
      word_update_k<<<1024, 256, 0, stream>>>(G, h, c, woutb, t);
    }
  }

  // ---- attention ----
  attlog_k<<<768, 256, 0, stream>>>(woutb, ws1b, ws2, logits);
  att_softmax_k<<<1024, 256, 0, stream>>>(woutb, logits, tok, att, attb);

  // ---- x-parts of conv/session LSTMs (bf16 MFMA, bias folded) ----
  mmabt_k<2><<<dim3(16,16), 256, 0, stream>>>(attb, cwihb, cb, nullptr, xwc);
  mmabt_k<1><<<dim3(16,16), 256, 0, stream>>>(attb, swihb, sb, perm, xws);

  // ---- conv + sess recurrent LSTMs (512-thr / 128-VGPR tier) ----
  recur4_k<<<40, 512, RECUR_LDS_BYTES, stream>>>(xwc, w16c, convb, xws, w16s, soutb);

  // ---- parallel state "scan" ----
  scan_prep_k<<<1024, 256, 0, stream>>>(soutb, convb, stm, statem, onec);
  gemm_abt64_k<false,true,true,false><<<dim3(16,4), 256, 0, stream>>>(
    onec, nullptr, Wp, bp, statem, nullptr, 512, HIDN, SNUM*HIDN);

  // ---- final projection + scores + log_softmax ----
  gemm_abt64_k<false,true,true,true><<<dim3(16,4), 256, 0, stream>>>(
    att, convb, Ws, bs, upb, nullptr, 512, HIDN, HIDN);
  scores_k<<<1024, 256, 0, stream>>>(statem, upb, (float*)d_out);
}

// Round 13
// 1385.633 us; speedup vs baseline: 1.2308x; 1.2308x over previous
//
#include <hip/hip_runtime.h>
#include <hip/hip_bf16.h>
#include <math.h>

#define HIDN 256
#define GATES 1024
#define LLEN 128
#define WLEN 48
#define SNUM 5
#define PLEN 32
#define EMBD 256

typedef _Float16 f16;
typedef _Float16 h2_t __attribute__((ext_vector_type(2)));
typedef short short8_t __attribute__((ext_vector_type(8)));
typedef float f32x4 __attribute__((ext_vector_type(4)));

__device__ __forceinline__ float sigf(float x){ return 1.0f/(1.0f+expf(-x)); }

__device__ __forceinline__ unsigned short f2bf(float f){
  unsigned int x = __builtin_bit_cast(unsigned int, f);
  x += 0x7fffu + ((x >> 16) & 1u);
  return (unsigned short)(x >> 16);
}
__device__ __forceinline__ float bf2f(unsigned short u){
  unsigned int x = ((unsigned int)u) << 16;
  return __builtin_bit_cast(float, x);
}

__device__ __forceinline__ float fd2(unsigned int w, unsigned int h, float acc){
  h2_t wa = __builtin_bit_cast(h2_t, w);
  h2_t hb = __builtin_bit_cast(h2_t, h);
#if defined(__has_builtin)
#if __has_builtin(__builtin_amdgcn_fdot2)
  return __builtin_amdgcn_fdot2(wa, hb, acc, false);
#else
  return acc + (float)wa[0]*(float)hb[0] + (float)wa[1]*(float)hb[1];
#endif
#else
  return acc + (float)wa[0]*(float)hb[0] + (float)wa[1]*(float)hb[1];
#endif
}
__device__ __forceinline__ float dot8(uint4 w, uint4 h, float acc){
  acc = fd2(w.x, h.x, acc);
  acc = fd2(w.y, h.y, acc);
  acc = fd2(w.z, h.z, acc);
  acc = fd2(w.w, h.w, acc);
  return acc;
}

// =======================================================================
// fp32 tiled GEMM (Wp / Ws final projections)
// =======================================================================
template<bool GATHER, bool BIAS, bool RELU, bool SPLIT>
__global__ __launch_bounds__(256) void gemm_abt64_k(
  const float* __restrict__ A, const float* __restrict__ A2,
  const float* __restrict__ Bm, const float* __restrict__ bias,
  float* __restrict__ C, const int* __restrict__ gidx,
  int K, int N, int ostride)
{
  __shared__ float As[32][68];
  __shared__ float Bs[32][68];
  const int tid = threadIdx.x;
  const int m0 = blockIdx.x*64, n0 = blockIdx.y*64;
  const int tx = tid & 15, ty = tid >> 4;
  const int lr = tid >> 3;
  const int lc = (tid & 7) * 4;
  float acc[4][4] = {};
  for (int k0 = 0; k0 < K; k0 += 32){
    #pragma unroll
    for (int hf = 0; hf < 2; ++hf){
      const int r = lr + hf*32;
      int am = m0 + r;
      if (GATHER) am = gidx[am];
      const float* asrc;
      if (SPLIT){
        if (k0 < 256) asrc = A  + (size_t)am*256 + k0 + lc;
        else          asrc = A2 + (size_t)am*256 + (k0-256) + lc;
      } else {
        asrc = A + (size_t)am*K + k0 + lc;
      }
      float4 av = *reinterpret_cast<const float4*>(asrc);
      float4 bv = *reinterpret_cast<const float4*>(Bm + (size_t)(n0+r)*K + k0 + lc);
      As[lc+0][r]=av.x; As[lc+1][r]=av.y; As[lc+2][r]=av.z; As[lc+3][r]=av.w;
      Bs[lc+0][r]=bv.x; Bs[lc+1][r]=bv.y; Bs[lc+2][r]=bv.z; Bs[lc+3][r]=bv.w;
    }
    __syncthreads();
    #pragma unroll
    for (int kk = 0; kk < 32; ++kk){
      const float4 a = *reinterpret_cast<const float4*>(&As[kk][ty*4]);
      const float4 b = *reinterpret_cast<const float4*>(&Bs[kk][tx*4]);
      acc[0][0] += a.x*b.x; acc[0][1] += a.x*b.y; acc[0][2] += a.x*b.z; acc[0][3] += a.x*b.w;
      acc[1][0] += a.y*b.x; acc[1][1] += a.y*b.y; acc[1][2] += a.y*b.z; acc[1][3] += a.y*b.w;
      acc[2][0] += a.z*b.x; acc[2][1] += a.z*b.y; acc[2][2] += a.z*b.z; acc[2][3] += a.z*b.w;
      acc[3][0] += a.w*b.x; acc[3][1] += a.w*b.y; acc[3][2] += a.w*b.z; acc[3][3] += a.w*b.w;
    }
    __syncthreads();
  }
  float4 bb;
  if (BIAS) bb = *reinterpret_cast<const float4*>(bias + n0 + tx*4);
  else      { bb.x=0.f; bb.y=0.f; bb.z=0.f; bb.w=0.f; }
  #pragma unroll
  for (int i = 0; i < 4; ++i){
    float4 o;
    o.x = acc[i][0]+bb.x; o.y = acc[i][1]+bb.y; o.z = acc[i][2]+bb.z; o.w = acc[i][3]+bb.w;
    if (RELU){ o.x=fmaxf(o.x,0.f); o.y=fmaxf(o.y,0.f); o.z=fmaxf(o.z,0.f); o.w=fmaxf(o.w,0.f); }
    *reinterpret_cast<float4*>(C + (size_t)(m0+ty*4+i)*ostride + n0 + tx*4) = o;
  }
}

// converters
__global__ __launch_bounds__(256) void cvt2_k(
  const float* __restrict__ a, const float* __restrict__ b,
  unsigned short* __restrict__ oa, unsigned short* __restrict__ ob, int n)
{
  for (int i = blockIdx.x*256 + threadIdx.x; i < n; i += gridDim.x*256){
    oa[i] = f2bf(a[i]);
    ob[i] = f2bf(b[i]);
  }
}
__global__ __launch_bounds__(256) void cvt1_k(
  const float* __restrict__ a, unsigned short* __restrict__ o, int n)
{
  for (int i = blockIdx.x*256 + threadIdx.x; i < n; i += gridDim.x*256)
    o[i] = f2bf(a[i]);
}
__global__ __launch_bounds__(256) void cvt_w16_k(
  const float* __restrict__ a, const float* __restrict__ b,
  f16* __restrict__ oa, f16* __restrict__ ob)
{
  const int i = blockIdx.x*256 + threadIdx.x;
  oa[i] = (f16)a[i];
  ob[i] = (f16)b[i];
}

// =======================================================================
// bf16 MFMA GEMM (xwc/xws paths): C(Mx1024) = A(Mx256) @ W(1024x256)^T + b
// =======================================================================
template<int AMODE>
__global__ __launch_bounds__(256) void mmabt_k(
  const void* __restrict__ Asrc, const unsigned short* __restrict__ Wb,
  const float* __restrict__ bias, const int* __restrict__ gidx,
  float* __restrict__ Cout)
{
  __shared__ char As[32768];
  const int tid = threadIdx.x;
  const int w = tid >> 6, l = tid & 63;
  const int lr = l & 15, lg = l >> 4;
  const int m0 = blockIdx.x*64, n0 = blockIdx.y*64;
  #pragma unroll
  for (int q = 0; q < 8; ++q){
    const int ck = tid*8 + q;
    const int rl = ck >> 5, o16 = ck & 31;
    int row = m0 + rl;
    if (AMODE == 1) row = gidx[row];
    char* dst = As + rl*512 + ((o16*16) ^ ((rl & 7) << 4));
    *reinterpret_cast<short8_t*>(dst) = *reinterpret_cast<const short8_t*>(
        (const unsigned short*)Asrc + (size_t)row*256 + o16*8);
  }
  __syncthreads();
  short8_t a[8];
  #pragma unroll
  for (int ks = 0; ks < 8; ++ks){
    const int rl = w*16 + lr;
    a[ks] = *reinterpret_cast<const short8_t*>(As + rl*512 + ((ks*64 + lg*16) ^ ((rl & 7) << 4)));
  }
  #pragma unroll
  for (int nt = 0; nt < 4; ++nt){
    f32x4 acc = f32x4{0,0,0,0};
    const int n = n0 + nt*16 + lr;
    #pragma unroll
    for (int ks = 0; ks < 8; ++ks){
      short8_t b = *reinterpret_cast<const short8_t*>(Wb + (size_t)n*256 + ks*32 + lg*8);
      acc = __builtin_amdgcn_mfma_f32_16x16x32_bf16(a[ks], b, acc, 0, 0, 0);
    }
    const float bn = bias[n];
    #pragma unroll
    for (int r = 0; r < 4; ++r){
      const int m = m0 + w*16 + lg*4 + r;
      Cout[(size_t)m*1024 + n] = acc[r] + bn;
    }
  }
}

// =======================================================================
// X-GEMM with packed gate-interleaved output; gather index computed
// inline from tok (row m -> t=m>>10, u=m&1023, token=tok[u*48+t]).
// =======================================================================
__global__ __launch_bounds__(256) void xgemm4_k(
  const float* __restrict__ emb, const unsigned short* __restrict__ Wb,
  const float* __restrict__ bias, const int* __restrict__ tok,
  unsigned short* __restrict__ Xp)
{
  __shared__ char As[32768];
  const int tid = threadIdx.x;
  const int w = tid >> 6, l = tid & 63;
  const int lr = l & 15, lg = l >> 4;
  const int m0 = blockIdx.x*64;
  const int j0 = blockIdx.y*64;
  #pragma unroll
  for (int q = 0; q < 8; ++q){
    const int ck = tid*8 + q;
    const int rl = ck >> 5, o16 = ck & 31;
    const int m = m0 + rl;
    const int tt = m >> 10, uu = m & 1023;
    const int row = tok[uu*WLEN + tt];
    const float* src = emb + (size_t)row*256 + o16*8;
    float4 f0 = *reinterpret_cast<const float4*>(src);
    float4 f1 = *reinterpret_cast<const float4*>(src + 4);
    union { short8_t s; unsigned short u[8]; } pk;
    pk.u[0]=f2bf(f0.x); pk.u[1]=f2bf(f0.y); pk.u[2]=f2bf(f0.z); pk.u[3]=f2bf(f0.w);
    pk.u[4]=f2bf(f1.x); pk.u[5]=f2bf(f1.y); pk.u[6]=f2bf(f1.z); pk.u[7]=f2bf(f1.w);
    *reinterpret_cast<short8_t*>(As + rl*512 + ((o16*16) ^ ((rl & 7) << 4))) = pk.s;
  }
  __syncthreads();
  const int jw = j0 + w*16;
  float bs_g[4];
  #pragma unroll
  for (int g = 0; g < 4; ++g) bs_g[g] = bias[g*256 + jw + lr];
  #pragma unroll
  for (int mt = 0; mt < 4; ++mt){
    short8_t a[8];
    const int rl = mt*16 + lr;
    #pragma unroll
    for (int ks = 0; ks < 8; ++ks)
      a[ks] = *reinterpret_cast<const short8_t*>(
          As + rl*512 + ((ks*64 + lg*16) ^ ((rl & 7) << 4)));
    f32x4 acc[4];
    #pragma unroll
    for (int g = 0; g < 4; ++g){
      acc[g] = f32x4{0,0,0,0};
      const unsigned short* wb = Wb + (size_t)(g*256 + jw + lr)*256 + lg*8;
      #pragma unroll
      for (int ks = 0; ks < 8; ++ks){
        short8_t b = *reinterpret_cast<const short8_t*>(wb + ks*32);
        acc[g] = __builtin_amdgcn_mfma_f32_16x16x32_bf16(a[ks], b, acc[g], 0, 0, 0);
      }
    }
    #pragma unroll
    for (int r = 0; r < 4; ++r){
      const int m = m0 + mt*16 + lg*4 + r;
      unsigned long long pk =
          (unsigned long long)f2bf(acc[0][r] + bs_g[0])
        | ((unsigned long long)f2bf(acc[1][r] + bs_g[1]) << 16)
        | ((unsigned long long)f2bf(acc[2][r] + bs_g[2]) << 32)
        | ((unsigned long long)f2bf(acc[3][r] + bs_g[3]) << 48);
      *reinterpret_cast<unsigned long long*>(Xp + (size_t)m*1024 + (jw + lr)*4) = pk;
    }
  }
}

// =======================================================================
// Word LSTM v7: 64 blocks x 1024 threads (16 waves, 4/SIMD TLP).
// Wave owns 16 j x 4 gates. o-gate LDS-resident (XOR-swizzled);
// i/f/g explicitly streamed via 2-deep ks software pipeline (6 short8
// bufs = 24 in-flight VGPRs, sized to the measured 64-reg grant).
// X prefetched at step start. h bf16 dbuf LDS. Zero cross-block sync.
// =======================================================================
__global__ __launch_bounds__(1024, 1) void word7_k(
  const unsigned short* __restrict__ Xp,   // [t*1024+seq][j*4+gate] bf16
  const unsigned short* __restrict__ Wb,   // uWhh bf16 [1024][256]
  unsigned short* __restrict__ woutb)      // [seq][t][256] bf16
{
  extern __shared__ char smem[];
  const int tid = threadIdx.x;
  const int w = tid >> 6, l = tid & 63;
  const int lr = l & 15, lg = l >> 4;
  const int S0 = blockIdx.x * 16;
  const int jb = w * 16;
  char* olds = smem + w*8192;              // wave-local o-gate: 16 rows x 512 B
  char* hb0  = smem + 131072;
  char* hb1  = smem + 139264;

  // zero both h buffers (16 KB)
  reinterpret_cast<uint4*>(hb0)[tid] = uint4{0,0,0,0};

  // stage o-gate slice: rows 768 + jb + 0..15
  #pragma unroll
  for (int q = 0; q < 8; ++q){
    const int ck = l*8 + q;
    const int rl = ck >> 5, o16 = ck & 31;
    short8_t v = *reinterpret_cast<const short8_t*>(
        Wb + (size_t)(768 + jb + rl)*256 + o16*8);
    *reinterpret_cast<short8_t*>(olds + rl*512 + ((o16*16) ^ ((rl & 7) << 4))) = v;
  }
  const unsigned short* ibase = Wb + (size_t)(      jb + lr)*256 + lg*8;
  const unsigned short* fbase = Wb + (size_t)(256 + jb + lr)*256 + lg*8;
  const unsigned short* gbase = Wb + (size_t)(512 + jb + lr)*256 + lg*8;
  float c_reg[4] = {0.f, 0.f, 0.f, 0.f};
  __syncthreads();

  for (int t = 0; t < WLEN; ++t){
    const char* hr = (t & 1) ? hb1 : hb0;
    char* hw = (t & 1) ? hb0 : hb1;
    const unsigned short* pi = ibase;
    const unsigned short* pf = fbase;
    const unsigned short* pg = gbase;
    asm volatile("" : "+v"(pi), "+v"(pf), "+v"(pg));   // re-stream each step
    // prefetch X for this step (hides under MFMA chain)
    unsigned long long xv[4];
    #pragma unroll
    for (int r = 0; r < 4; ++r)
      xv[r] = *reinterpret_cast<const unsigned long long*>(
          Xp + ((size_t)t*1024 + (S0 + lg*4 + r))*1024 + (jb + lr)*4);
    // 2-deep ks pipeline of i/f/g B-frags
    short8_t bi[2], bf[2], bg[2];
    bi[0] = *reinterpret_cast<const short8_t*>(pi);
    bf[0] = *reinterpret_cast<const short8_t*>(pf);
    bg[0] = *reinterpret_cast<const short8_t*>(pg);
    bi[1] = *reinterpret_cast<const short8_t*>(pi + 32);
    bf[1] = *reinterpret_cast<const short8_t*>(pf + 32);
    bg[1] = *reinterpret_cast<const short8_t*>(pg + 32);
    f32x4 aI = f32x4{0,0,0,0}, aF = f32x4{0,0,0,0};
    f32x4 aG = f32x4{0,0,0,0}, aO = f32x4{0,0,0,0};
    #pragma unroll
    for (int ks = 0; ks < 8; ++ks){
      short8_t a = *reinterpret_cast<const short8_t*>(
          hr + lr*512 + ((ks*64 + lg*16) ^ ((lr & 7) << 4)));
      short8_t bo = *reinterpret_cast<const short8_t*>(
          olds + lr*512 + ((ks*64 + lg*16) ^ ((lr & 7) << 4)));
      const short8_t ci = bi[ks & 1], cf = bf[ks & 1], cg = bg[ks & 1];
      if (ks + 2 < 8){
        bi[ks & 1] = *reinterpret_cast<const short8_t*>(pi + (ks+2)*32);
        bf[ks & 1] = *reinterpret_cast<const short8_t*>(pf + (ks+2)*32);
        bg[ks & 1] = *reinterpret_cast<const short8_t*>(pg + (ks+2)*32);
      }
      aI = __builtin_amdgcn_mfma_f32_16x16x32_bf16(a, ci, aI, 0, 0, 0);
      aF = __builtin_amdgcn_mfma_f32_16x16x32_bf16(a, cf, aF, 0, 0, 0);
      aG = __builtin_amdgcn_mfma_f32_16x16x32_bf16(a, cg, aG, 0, 0, 0);
      aO = __builtin_amdgcn_mfma_f32_16x16x32_bf16(a, bo, aO, 0, 0, 0);
    }
    const int j = jb + lr;
    #pragma unroll
    for (int r = 0; r < 4; ++r){
      const int s = lg*4 + r;
      float gi = aI[r] + bf2f((unsigned short)(xv[r]));
      float gf = aF[r] + bf2f((unsigned short)(xv[r] >> 16));
      float gg = aG[r] + bf2f((unsigned short)(xv[r] >> 32));
      float go = aO[r] + bf2f((unsigned short)(xv[r] >> 48));
      float cc = sigf(gf)*c_reg[r] + sigf(gi)*tanhf(gg);
      c_reg[r] = cc;
      float hh = sigf(go)*tanhf(cc);
      unsigned short h16 = f2bf(hh);
      woutb[((size_t)(S0+s)*WLEN + t)*256 + j] = h16;
      *reinterpret_cast<unsigned short*>(hw + s*512 + ((j*2) ^ ((s & 7) << 4))) = h16;
    }
    __syncthreads();
  }
}

// =======================================================================
// conv + sess recurrent LSTM v3 (r9 exact — 413 us proven): 1024 thr,
// one f16 gate-row/thread, k<192 in wr[24], k>=192 in 128 KB LDS.
// blocks 0..7: conv (T=128); 8..39: sess (T=32).
// =======================================================================
__global__ __launch_bounds__(1024) void recur3_k(
  const float* __restrict__ xwc, const f16* __restrict__ w16c, float* __restrict__ convb,
  const float* __restrict__ xws, const f16* __restrict__ w16s, float* __restrict__ soutb)
{
  const float* xw; const f16* w16; float* out; int seq, T;
  if (blockIdx.x < 8){ seq = blockIdx.x;     T = 128; xw = xwc; w16 = w16c; out = convb; }
  else               { seq = blockIdx.x - 8; T = 32;  xw = xws; w16 = w16s; out = soutb; }

  extern __shared__ char smem[];
  uint4* w_lds  = (uint4*)smem;
  float* g_s    = (float*)(smem + 131072);
  f16*   h_half = (f16*)(smem + 131072 + 4096);
  const uint4* h4 = (const uint4*)h_half;

  const int tid = threadIdx.x;
  #pragma unroll
  for (int cth = 0; cth < 8; ++cth)
    w_lds[cth*1024 + tid] = *reinterpret_cast<const uint4*>(w16 + (size_t)tid*256 + 192 + cth*8);
  uint4 wr[24];
  #pragma unroll
  for (int cth = 0; cth < 24; ++cth)
    wr[cth] = *reinterpret_cast<const uint4*>(w16 + (size_t)tid*256 + cth*8);
  if (tid < 32) reinterpret_cast<uint4*>(h_half)[tid] = uint4{0,0,0,0};
  float c_reg = 0.f;
  __syncthreads();

  for (int t = 0; t < T; ++t){
    float acc = xw[(size_t)(seq*T + t)*GATES + tid];
    float a0 = 0.f, a1 = 0.f;
    #pragma unroll
    for (int k = 0; k < 24; k += 2){
      const uint4 h0 = h4[k], h1 = h4[k+1];
      a0 = dot8(wr[k],   h0, a0);
      a1 = dot8(wr[k+1], h1, a1);
    }
    #pragma unroll
    for (int cth = 0; cth < 8; cth += 2){
      const uint4 h0 = h4[24+cth], h1 = h4[25+cth];
      a0 = dot8(w_lds[cth*1024 + tid],     h0, a0);
      a1 = dot8(w_lds[(cth+1)*1024 + tid], h1, a1);
    }
    g_s[tid] = acc + a0 + a1;
    __syncthreads();
    if (tid < HIDN){
      const int j = tid;
      float gi = g_s[j], gf = g_s[HIDN+j], gg = g_s[2*HIDN+j], go = g_s[3*HIDN+j];
      float cc = sigf(gf)*c_reg + sigf(gi)*tanhf(gg);
      c_reg = cc;
      float hh = sigf(go)*tanhf(cc);
      h_half[j] = (f16)hh;
      out[(size_t)(seq*T + t)*HIDN + j] = hh;
    }
    __syncthreads();
  }
}

// =======================================================================
// attention logits via bf16 MFMA + fused tanh/ws2 contraction
// =======================================================================
__global__ __launch_bounds__(256) void attlog_k(
  const unsigned short* __restrict__ woutb, const unsigned short* __restrict__ ws1b,
  const float* __restrict__ ws2, float* __restrict__ logits)
{
  const int tid = threadIdx.x;
  const int w = tid >> 6, l = tid & 63;
  const int lr = l & 15, lg = l >> 4;
  const int m0 = blockIdx.x*64;
  short8_t a[8];
  #pragma unroll
  for (int ks = 0; ks < 8; ++ks){
    const int m = m0 + w*16 + lr;
    a[ks] = *reinterpret_cast<const short8_t*>(woutb + (size_t)m*256 + ks*32 + lg*8);
  }
  float part[4] = {0.f, 0.f, 0.f, 0.f};
  #pragma unroll
  for (int nt = 0; nt < 16; ++nt){
    f32x4 acc = f32x4{0,0,0,0};
    const int n = nt*16 + lr;
    #pragma unroll
    for (int ks = 0; ks < 8; ++ks){
      short8_t b = *reinterpret_cast<const short8_t*>(ws1b + (size_t)n*256 + ks*32 + lg*8);
      acc = __builtin_amdgcn_mfma_f32_16x16x32_bf16(a[ks], b, acc, 0, 0, 0);
    }
    const float w2 = ws2[n];
    #pragma unroll
    for (int r = 0; r < 4; ++r) part[r] += w2 * tanhf(acc[r]);
  }
  #pragma unroll
  for (int r = 0; r < 4; ++r){
    float p = part[r];
    p += __shfl_xor(p, 1, 64);
    p += __shfl_xor(p, 2, 64);
    p += __shfl_xor(p, 4, 64);
    p += __shfl_xor(p, 8, 64);
    if (lr == 0) logits[m0 + w*16 + lg*4 + r] = p;
  }
}

// masked softmax over W + weighted sum -> att fp32 + attb bf16
__global__ __launch_bounds__(256) void att_softmax_k(
  const unsigned short* __restrict__ woutb, const float* __restrict__ logits,
  const int* __restrict__ tok, float* __restrict__ att, unsigned short* __restrict__ attb)
{
  __shared__ float e[WLEN];
  __shared__ float den_s;
  const int n = blockIdx.x, j = threadIdx.x;
  if (j < WLEN){
    float lgt = logits[n*WLEN + j];
    if (tok[n*WLEN + j] == 0) lgt -= 10000.0f;
    e[j] = lgt;
  }
  __syncthreads();
  if (j == 0){
    float mx = -1e30f;
    for (int ww = 0; ww < WLEN; ++ww) mx = fmaxf(mx, e[ww]);
    float den = 0.f;
    for (int ww = 0; ww < WLEN; ++ww){ float ee = expf(e[ww]-mx); e[ww] = ee; den += ee; }
    den_s = den;
  }
  __syncthreads();
  const float inv = 1.0f/den_s;
  float a = 0.f;
  for (int ww = 0; ww < WLEN; ++ww)
    a += e[ww]*bf2f(woutb[((size_t)n*WLEN + ww)*HIDN + j]);
  a *= inv;
  att[(size_t)n*HIDN + j] = a;
  attb[(size_t)n*HIDN + j] = f2bf(a);
}

// =======================================================================
// Fallback word LSTM (fp32, only if workspace too small for X)
// =======================================================================
__global__ __launch_bounds__(256) void word_gates_k(
    const int* __restrict__ tok, const float* __restrict__ emb,
    const float* __restrict__ Wih, const float* __restrict__ Whh,
    const float* __restrict__ bias, const float* __restrict__ hbuf,
    float* __restrict__ G, int t)
{
  __shared__ float As[32][68];
  __shared__ float Bs[32][68];
  const int tid = threadIdx.x;
  const int m0 = blockIdx.x*64, n0 = blockIdx.y*64;
  const int tx = tid & 15, ty = tid >> 4;
  const int lr = tid >> 3;
  const int lc = (tid & 7) * 4;
  float acc[4][4] = {};
  for (int kt = 0; kt < 16; ++kt){
    const int k0 = (kt & 7)*32;
    const bool xp = (kt < 8);
    #pragma unroll
    for (int hf = 0; hf < 2; ++hf){
      const int r = lr + hf*32;
      float4 av, bv;
      if (xp){
        const int token = tok[(m0+r)*WLEN + t];
        av = *reinterpret_cast<const float4*>(emb + (size_t)token*EMBD + k0 + lc);
      } else {
        av = *reinterpret_cast<const float4*>(hbuf + (size_t)(m0+r)*HIDN + k0 + lc);
      }
      const float* bptr = (xp ? Wih : Whh) + (size_t)(n0+r)*HIDN + k0 + lc;
      bv = *reinterpret_cast<const float4*>(bptr);
      As[lc+0][r]=av.x; As[lc+1][r]=av.y; As[lc+2][r]=av.z; As[lc+3][r]=av.w;
      Bs[lc+0][r]=bv.x; Bs[lc+1][r]=bv.y; Bs[lc+2][r]=bv.z; Bs[lc+3][r]=bv.w;
    }
    __syncthreads();
    #pragma unroll
    for (int kk = 0; kk < 32; ++kk){
      const float4 a = *reinterpret_cast<const float4*>(&As[kk][ty*4]);
      const float4 b = *reinterpret_cast<const float4*>(&Bs[kk][tx*4]);
      acc[0][0] += a.x*b.x; acc[0][1] += a.x*b.y; acc[0][2] += a.x*b.z; acc[0][3] += a.x*b.w;
      acc[1][0] += a.y*b.x; acc[1][1] += a.y*b.y; acc[1][2] += a.y*b.z; acc[1][3] += a.y*b.w;
      acc[2][0] += a.z*b.x; acc[2][1] += a.z*b.y; acc[2][2] += a.z*b.z; acc[2][3] += a.z*b.w;
      acc[3][0] += a.w*b.x; acc[3][1] += a.w*b.y; acc[3][2] += a.w*b.z; acc[3][3] += a.w*b.w;
    }
    __syncthreads();
  }
  const float4 bb = *reinterpret_cast<const float4*>(bias + n0 + tx*4);
  #pragma unroll
  for (int i = 0; i < 4; ++i){
    float4 o;
    o.x = acc[i][0]+bb.x; o.y = acc[i][1]+bb.y; o.z = acc[i][2]+bb.z; o.w = acc[i][3]+bb.w;
    *reinterpret_cast<float4*>(G + (size_t)(m0+ty*4+i)*GATES + n0 + tx*4) = o;
  }
}

__global__ __launch_bounds__(256) void word_update_k(
  const float* __restrict__ G, float* __restrict__ h, float* __restrict__ c,
  unsigned short* __restrict__ woutb, int t)
{
  int idx = blockIdx.x*256 + threadIdx.x;
  int m = idx >> 8, j = idx & 255;
  const float* g = G + (size_t)m*GATES;
  float gi = g[j], gf = g[HIDN+j], gg = g[2*HIDN+j], go = g[3*HIDN+j];
  float cc = c[idx];
  cc = sigf(gf)*cc + sigf(gi)*tanhf(gg);
  float hh = sigf(go)*tanhf(cc);
  c[idx] = cc; h[idx] = hh;
  woutb[(size_t)m*WLEN*HIDN + (size_t)t*HIDN + j] = f2bf(hh);
}

// =======================================================================
// Parallel state "scan" prep
// =======================================================================
__global__ __launch_bounds__(256) void scan_prep_k(
  const float* __restrict__ sess_out, const float* __restrict__ conv_out,
  const int* __restrict__ stm, float* __restrict__ state, float* __restrict__ onec)
{
  const int bl = blockIdx.x;
  const int b = bl >> 7, l = bl & 127;
  const int j = threadIdx.x;
  float ones = 0.f;
  #pragma unroll
  for (int s = 1; s < SNUM; ++s){
    const int sv = stm[(size_t)bl*SNUM + s];
    float vg = 0.f;
    if (sv > 0){
      int p = sv - 1; if (p > PLEN-1) p = PLEN-1;
      vg = sess_out[((size_t)(b*4 + (s-1))*PLEN + p)*HIDN + j];
    }
    float v = vg;
    if (sv == -1){
      v = 0.f;
      if (l > 0){
        const int pv = stm[(size_t)(bl-1)*SNUM + s];
        if (pv > 0){
          int p2 = pv - 1; if (p2 > PLEN-1) p2 = PLEN-1;
          v = sess_out[((size_t)(b*4 + (s-1))*PLEN + p2)*HIDN + j];
        }
      }
    }
    if (sv != 0) ones += v;
    state[((size_t)bl*SNUM + s)*HIDN + j] = vg;
  }
  onec[(size_t)bl*(2*HIDN) + j] = ones * 0.25f;
  const int lp = (l == 0) ? 0 : (l-1);
  onec[(size_t)bl*(2*HIDN) + HIDN + j] = conv_out[((size_t)(b*LLEN + lp))*HIDN + j];
}

// =======================================================================
// final scores + log_softmax
// =======================================================================
__global__ __launch_bounds__(256) void scores_k(
  const float* __restrict__ state, const float* __restrict__ up, float* __restrict__ out)
{
  const int n = blockIdx.x, j = threadIdx.x;
  __shared__ float red[SNUM][4];
  const float u = up[(size_t)n*HIDN + j];
  const int lane = j & 63, wid = j >> 6;
  #pragma unroll
  for (int s = 0; s < SNUM; ++s){
    float p = state[((size_t)n*SNUM + s)*HIDN + j]*u;
    for (int off = 32; off; off >>= 1) p += __shfl_down(p, off, 64);
    if (lane == 0) red[s][wid] = p;
  }
  __syncthreads();
  if (j == 0){
    float sc[SNUM]; float mx = -1e30f;
    #pragma unroll
    for (int s = 0; s < SNUM; ++s){
      sc[s] = red[s][0]+red[s][1]+red[s][2]+red[s][3];
      mx = fmaxf(mx, sc[s]);
    }
    float den = 0.f;
    #pragma unroll
    for (int s = 0; s < SNUM; ++s) den += expf(sc[s]-mx);
    const float ls = logf(den);
    #pragma unroll
    for (int s = 0; s < SNUM; ++s) out[(size_t)n*SNUM + s] = sc[s]-mx-ls;
  }
}

// ---------------- workspace layout (float offsets) ----------------
static const size_t OFF_G     = 0;                        // fallback
static const size_t OFF_H     = OFF_G     + 1048576;
static const size_t OFF_C     = OFF_H     + 262144;
static const size_t OFF_ATT   = OFF_C     + 262144;
static const size_t OFF_ATTB  = OFF_ATT   + 262144;       // bf16 att
static const size_t OFF_XWC   = OFF_ATTB  + 131072;
static const size_t OFF_XWS   = OFF_XWC   + 1048576;
static const size_t OFF_CONV  = OFF_XWS   + 1048576;
static const size_t OFF_SOUT  = OFF_CONV  + 262144;
static const size_t OFF_STATE = OFF_SOUT  + 262144;
static const size_t OFF_ONEC  = OFF_STATE + 1310720;
static const size_t OFF_UP    = OFF_ONEC  + 524288;
static const size_t OFF_LOG   = OFF_UP    + 262144;
static const size_t OFF_UWHHB = OFF_LOG   + 49152;        // bf16 uWhh
static const size_t OFF_WIHB  = OFF_UWHHB + 131072;       // bf16 uWih
static const size_t OFF_WS1B  = OFF_WIHB  + 131072;       // bf16 ws1
static const size_t OFF_CWIHB = OFF_WS1B  + 32768;        // bf16 cWih
static const size_t OFF_SWIHB = OFF_CWIHB + 131072;       // bf16 sWih
static const size_t OFF_W16C  = OFF_SWIHB + 131072;       // f16 cWhh
static const size_t OFF_W16S  = OFF_W16C  + 131072;       // f16 sWhh
static const size_t OFF_WOUTB = OFF_W16S  + 131072;       // bf16 wout
static const size_t OFF_X     = OFF_WOUTB + 6291456;      // bf16 X (gate-interleaved)
static const size_t NEED_X_FLOATS = OFF_X + (size_t)49152*512;

static const size_t WORD_LDS_BYTES  = 131072 + 16384;         // 147456
static const size_t RECUR_LDS_BYTES = 131072 + 4096 + 512;    // 135680

extern "C" void kernel_launch(void* const* d_in, const int* in_sizes, int n_in,
                              void* d_out, int out_size, void* d_ws, size_t ws_size,
                              hipStream_t stream)
{
  const int*   tok   = (const int*)  d_in[0];
  const int*   perm  = (const int*)  d_in[2];
  const int*   stm   = (const int*)  d_in[3];
  const float* emb   = (const float*)d_in[5];
  const float* uWih  = (const float*)d_in[6];
  const float* uWhh  = (const float*)d_in[7];
  const float* ub    = (const float*)d_in[8];
  const float* ws1   = (const float*)d_in[9];
  const float* ws2   = (const float*)d_in[10];
  const float* cWih  = (const float*)d_in[11];
  const float* cWhh  = (const float*)d_in[12];
  const float* cb    = (const float*)d_in[13];
  const float* sWih  = (const float*)d_in[14];
  const float* sWhh  = (const float*)d_in[15];
  const float* sb    = (const float*)d_in[16];
  const float* Wp    = (const float*)d_in[17];
  const float* bp    = (const float*)d_in[18];
  const float* Ws    = (const float*)d_in[19];
  const float* bs    = (const float*)d_in[20];

  float* wsf    = (float*)d_ws;
  float* G      = wsf + OFF_G;
  float* h      = wsf + OFF_H;
  float* c      = wsf + OFF_C;
  float* att    = wsf + OFF_ATT;
  float* xwc    = wsf + OFF_XWC;
  float* xws    = wsf + OFF_XWS;
  float* convb  = wsf + OFF_CONV;
  float* soutb  = wsf + OFF_SOUT;
  float* statem = wsf + OFF_STATE;
  float* onec   = wsf + OFF_ONEC;
  float* upb    = wsf + OFF_UP;
  float* logits = wsf + OFF_LOG;
  unsigned short* attb  = (unsigned short*)(wsf + OFF_ATTB);
  unsigned short* uwhhb = (unsigned short*)(wsf + OFF_UWHHB);
  unsigned short* wihb  = (unsigned short*)(wsf + OFF_WIHB);
  unsigned short* ws1b  = (unsigned short*)(wsf + OFF_WS1B);
  unsigned short* cwihb = (unsigned short*)(wsf + OFF_CWIHB);
  unsigned short* swihb = (unsigned short*)(wsf + OFF_SWIHB);
  f16*   w16c   = (f16*)(wsf + OFF_W16C);
  f16*   w16s   = (f16*)(wsf + OFF_W16S);
  unsigned short* woutb = (unsigned short*)(wsf + OFF_WOUTB);
  unsigned short* X16   = (unsigned short*)(wsf + OFF_X);

  const bool useX = ws_size >= NEED_X_FLOATS*sizeof(float);

  hipFuncSetAttribute(reinterpret_cast<const void*>(word7_k),
                      hipFuncAttributeMaxDynamicSharedMemorySize, (int)WORD_LDS_BYTES);
  hipFuncSetAttribute(reinterpret_cast<const void*>(recur3_k),
                      hipFuncAttributeMaxDynamicSharedMemorySize, (int)RECUR_LDS_BYTES);

  // weight conversions
  cvt2_k<<<256, 256, 0, stream>>>(uWhh, uWih, uwhhb, wihb, 262144);
  cvt2_k<<<256, 256, 0, stream>>>(cWih, sWih, cwihb, swihb, 262144);
  cvt_w16_k<<<1024, 256, 0, stream>>>(cWhh, sWhh, w16c, w16s);
  cvt1_k<<<64, 256, 0, stream>>>(ws1, ws1b, 65536);

  // ---- word LSTM ----
  if (useX){
    xgemm4_k<<<dim3(768,4), 256, 0, stream>>>(emb, wihb, ub, tok, X16);
    word7_k<<<64, 1024, WORD_LDS_BYTES, stream>>>(X16, uwhhb, woutb);
  } else {
    hipMemsetAsync(h, 0, 2*262144*sizeof(float), stream);
    for (int t = 0; t < WLEN; ++t){
      word_gates_k<<<dim3(16,16), 256, 0, stream>>>(tok, emb, uWih, uWhh, ub, h, G, t);
      word_update_k<<<1024, 256, 0, stream>>>(G, h, c, woutb, t);
    }
  }

  // ---- attention ----
  attlog_k<<<768, 256, 0, stream>>>(woutb, ws1b, ws2, logits);
  att_softmax_k<<<1024, 256, 0, stream>>>(woutb, logits, tok, att, attb);

  // ---- x-parts of conv/session LSTMs (bf16 MFMA, bias folded) ----
  mmabt_k<2><<<dim3(16,16), 256, 0, stream>>>(attb, cwihb, cb, nullptr, xwc);
  mmabt_k<1><<<dim3(16,16), 256, 0, stream>>>(attb, swihb, sb, perm, xws);

  // ---- conv + sess recurrent LSTMs (r9-proven full-stream config) ----
  recur3_k<<<40, 1024, RECUR_LDS_BYTES, stream>>>(xwc, w16c, convb, xws, w16s, soutb);

  // ---- parallel state "scan" ----
  scan_prep_k<<<1024, 256, 0, stream>>>(soutb, convb, stm, statem, onec);
  gemm_abt64_k<false,true,true,false><<<dim3(16,4), 256, 0, stream>>>(
    onec, nullptr, Wp, bp, statem, nullptr, 512, HIDN, SNUM*HIDN);

  // ---- final projection + scores + log_softmax ----
  gemm_abt64_k<false,true,true,true><<<dim3(16,4), 256, 0, stream>>>(
    att, convb, Ws, bs, upb, nullptr, 512, HIDN, HIDN);
  scores_k<<<1024, 256, 0, stream>>>(statem, upb, (float*)d_out);
}

// Round 14
// 1167.201 us; speedup vs baseline: 1.4611x; 1.1871x over previous
//
#include <hip/hip_runtime.h>
#include <hip/hip_bf16.h>
#include <math.h>

#define HIDN 256
#define GATES 1024
#define LLEN 128
#define WLEN 48
#define SNUM 5
#define PLEN 32
#define EMBD 256

typedef _Float16 f16;
typedef _Float16 h2_t __attribute__((ext_vector_type(2)));
typedef short short8_t __attribute__((ext_vector_type(8)));
typedef float f32x4 __attribute__((ext_vector_type(4)));

__device__ __forceinline__ float sigf(float x){ return 1.0f/(1.0f+expf(-x)); }

__device__ __forceinline__ unsigned short f2bf(float f){
  unsigned int x = __builtin_bit_cast(unsigned int, f);
  x += 0x7fffu + ((x >> 16) & 1u);
  return (unsigned short)(x >> 16);
}
__device__ __forceinline__ float bf2f(unsigned short u){
  unsigned int x = ((unsigned int)u) << 16;
  return __builtin_bit_cast(float, x);
}

__device__ __forceinline__ float fd2(unsigned int w, unsigned int h, float acc){
  h2_t wa = __builtin_bit_cast(h2_t, w);
  h2_t hb = __builtin_bit_cast(h2_t, h);
#if defined(__has_builtin)
#if __has_builtin(__builtin_amdgcn_fdot2)
  return __builtin_amdgcn_fdot2(wa, hb, acc, false);
#else
  return acc + (float)wa[0]*(float)hb[0] + (float)wa[1]*(float)hb[1];
#endif
#else
  return acc + (float)wa[0]*(float)hb[0] + (float)wa[1]*(float)hb[1];
#endif
}
__device__ __forceinline__ float dot8(uint4 w, uint4 h, float acc){
  acc = fd2(w.x, h.x, acc);
  acc = fd2(w.y, h.y, acc);
  acc = fd2(w.z, h.z, acc);
  acc = fd2(w.w, h.w, acc);
  return acc;
}

// =======================================================================
// fp32 tiled GEMM (Wp / Ws final projections)
// =======================================================================
template<bool GATHER, bool BIAS, bool RELU, bool SPLIT>
__global__ __launch_bounds__(256) void gemm_abt64_k(
  const float* __restrict__ A, const float* __restrict__ A2,
  const float* __restrict__ Bm, const float* __restrict__ bias,
  float* __restrict__ C, const int* __restrict__ gidx,
  int K, int N, int ostride)
{
  __shared__ float As[32][68];
  __shared__ float Bs[32][68];
  const int tid = threadIdx.x;
  const int m0 = blockIdx.x*64, n0 = blockIdx.y*64;
  const int tx = tid & 15, ty = tid >> 4;
  const int lr = tid >> 3;
  const int lc = (tid & 7) * 4;
  float acc[4][4] = {};
  for (int k0 = 0; k0 < K; k0 += 32){
    #pragma unroll
    for (int hf = 0; hf < 2; ++hf){
      const int r = lr + hf*32;
      int am = m0 + r;
      if (GATHER) am = gidx[am];
      const float* asrc;
      if (SPLIT){
        if (k0 < 256) asrc = A  + (size_t)am*256 + k0 + lc;
        else          asrc = A2 + (size_t)am*256 + (k0-256) + lc;
      } else {
        asrc = A + (size_t)am*K + k0 + lc;
      }
      float4 av = *reinterpret_cast<const float4*>(asrc);
      float4 bv = *reinterpret_cast<const float4*>(Bm + (size_t)(n0+r)*K + k0 + lc);
      As[lc+0][r]=av.x; As[lc+1][r]=av.y; As[lc+2][r]=av.z; As[lc+3][r]=av.w;
      Bs[lc+0][r]=bv.x; Bs[lc+1][r]=bv.y; Bs[lc+2][r]=bv.z; Bs[lc+3][r]=bv.w;
    }
    __syncthreads();
    #pragma unroll
    for (int kk = 0; kk < 32; ++kk){
      const float4 a = *reinterpret_cast<const float4*>(&As[kk][ty*4]);
      const float4 b = *reinterpret_cast<const float4*>(&Bs[kk][tx*4]);
      acc[0][0] += a.x*b.x; acc[0][1] += a.x*b.y; acc[0][2] += a.x*b.z; acc[0][3] += a.x*b.w;
      acc[1][0] += a.y*b.x; acc[1][1] += a.y*b.y; acc[1][2] += a.y*b.z; acc[1][3] += a.y*b.w;
      acc[2][0] += a.z*b.x; acc[2][1] += a.z*b.y; acc[2][2] += a.z*b.z; acc[2][3] += a.z*b.w;
      acc[3][0] += a.w*b.x; acc[3][1] += a.w*b.y; acc[3][2] += a.w*b.z; acc[3][3] += a.w*b.w;
    }
    __syncthreads();
  }
  float4 bb;
  if (BIAS) bb = *reinterpret_cast<const float4*>(bias + n0 + tx*4);
  else      { bb.x=0.f; bb.y=0.f; bb.z=0.f; bb.w=0.f; }
  #pragma unroll
  for (int i = 0; i < 4; ++i){
    float4 o;
    o.x = acc[i][0]+bb.x; o.y = acc[i][1]+bb.y; o.z = acc[i][2]+bb.z; o.w = acc[i][3]+bb.w;
    if (RELU){ o.x=fmaxf(o.x,0.f); o.y=fmaxf(o.y,0.f); o.z=fmaxf(o.z,0.f); o.w=fmaxf(o.w,0.f); }
    *reinterpret_cast<float4*>(C + (size_t)(m0+ty*4+i)*ostride + n0 + tx*4) = o;
  }
}

// converters
__global__ __launch_bounds__(256) void cvt2_k(
  const float* __restrict__ a, const float* __restrict__ b,
  unsigned short* __restrict__ oa, unsigned short* __restrict__ ob, int n)
{
  for (int i = blockIdx.x*256 + threadIdx.x; i < n; i += gridDim.x*256){
    oa[i] = f2bf(a[i]);
    ob[i] = f2bf(b[i]);
  }
}
__global__ __launch_bounds__(256) void cvt1_k(
  const float* __restrict__ a, unsigned short* __restrict__ o, int n)
{
  for (int i = blockIdx.x*256 + threadIdx.x; i < n; i += gridDim.x*256)
    o[i] = f2bf(a[i]);
}
__global__ __launch_bounds__(256) void cvt_w16_k(
  const float* __restrict__ a, const float* __restrict__ b,
  f16* __restrict__ oa, f16* __restrict__ ob)
{
  const int i = blockIdx.x*256 + threadIdx.x;
  oa[i] = (f16)a[i];
  ob[i] = (f16)b[i];
}

// =======================================================================
// bf16 MFMA GEMM (xwc/xws paths): C(Mx1024) = A(Mx256) @ W(1024x256)^T + b
// =======================================================================
template<int AMODE>
__global__ __launch_bounds__(256) void mmabt_k(
  const void* __restrict__ Asrc, const unsigned short* __restrict__ Wb,
  const float* __restrict__ bias, const int* __restrict__ gidx,
  float* __restrict__ Cout)
{
  __shared__ char As[32768];
  const int tid = threadIdx.x;
  const int w = tid >> 6, l = tid & 63;
  const int lr = l & 15, lg = l >> 4;
  const int m0 = blockIdx.x*64, n0 = blockIdx.y*64;
  #pragma unroll
  for (int q = 0; q < 8; ++q){
    const int ck = tid*8 + q;
    const int rl = ck >> 5, o16 = ck & 31;
    int row = m0 + rl;
    if (AMODE == 1) row = gidx[row];
    char* dst = As + rl*512 + ((o16*16) ^ ((rl & 7) << 4));
    *reinterpret_cast<short8_t*>(dst) = *reinterpret_cast<const short8_t*>(
        (const unsigned short*)Asrc + (size_t)row*256 + o16*8);
  }
  __syncthreads();
  short8_t a[8];
  #pragma unroll
  for (int ks = 0; ks < 8; ++ks){
    const int rl = w*16 + lr;
    a[ks] = *reinterpret_cast<const short8_t*>(As + rl*512 + ((ks*64 + lg*16) ^ ((rl & 7) << 4)));
  }
  #pragma unroll
  for (int nt = 0; nt < 4; ++nt){
    f32x4 acc = f32x4{0,0,0,0};
    const int n = n0 + nt*16 + lr;
    #pragma unroll
    for (int ks = 0; ks < 8; ++ks){
      short8_t b = *reinterpret_cast<const short8_t*>(Wb + (size_t)n*256 + ks*32 + lg*8);
      acc = __builtin_amdgcn_mfma_f32_16x16x32_bf16(a[ks], b, acc, 0, 0, 0);
    }
    const float bn = bias[n];
    #pragma unroll
    for (int r = 0; r < 4; ++r){
      const int m = m0 + w*16 + lg*4 + r;
      Cout[(size_t)m*1024 + n] = acc[r] + bn;
    }
  }
}

// =======================================================================
// X-GEMM with packed gate-interleaved output; gather index inline from tok
// =======================================================================
__global__ __launch_bounds__(256) void xgemm4_k(
  const float* __restrict__ emb, const unsigned short* __restrict__ Wb,
  const float* __restrict__ bias, const int* __restrict__ tok,
  unsigned short* __restrict__ Xp)
{
  __shared__ char As[32768];
  const int tid = threadIdx.x;
  const int w = tid >> 6, l = tid & 63;
  const int lr = l & 15, lg = l >> 4;
  const int m0 = blockIdx.x*64;
  const int j0 = blockIdx.y*64;
  #pragma unroll
  for (int q = 0; q < 8; ++q){
    const int ck = tid*8 + q;
    const int rl = ck >> 5, o16 = ck & 31;
    const int m = m0 + rl;
    const int tt = m >> 10, uu = m & 1023;
    const int row = tok[uu*WLEN + tt];
    const float* src = emb + (size_t)row*256 + o16*8;
    float4 f0 = *reinterpret_cast<const float4*>(src);
    float4 f1 = *reinterpret_cast<const float4*>(src + 4);
    union { short8_t s; unsigned short u[8]; } pk;
    pk.u[0]=f2bf(f0.x); pk.u[1]=f2bf(f0.y); pk.u[2]=f2bf(f0.z); pk.u[3]=f2bf(f0.w);
    pk.u[4]=f2bf(f1.x); pk.u[5]=f2bf(f1.y); pk.u[6]=f2bf(f1.z); pk.u[7]=f2bf(f1.w);
    *reinterpret_cast<short8_t*>(As + rl*512 + ((o16*16) ^ ((rl & 7) << 4))) = pk.s;
  }
  __syncthreads();
  const int jw = j0 + w*16;
  float bs_g[4];
  #pragma unroll
  for (int g = 0; g < 4; ++g) bs_g[g] = bias[g*256 + jw + lr];
  #pragma unroll
  for (int mt = 0; mt < 4; ++mt){
    short8_t a[8];
    const int rl = mt*16 + lr;
    #pragma unroll
    for (int ks = 0; ks < 8; ++ks)
      a[ks] = *reinterpret_cast<const short8_t*>(
          As + rl*512 + ((ks*64 + lg*16) ^ ((rl & 7) << 4)));
    f32x4 acc[4];
    #pragma unroll
    for (int g = 0; g < 4; ++g){
      acc[g] = f32x4{0,0,0,0};
      const unsigned short* wb = Wb + (size_t)(g*256 + jw + lr)*256 + lg*8;
      #pragma unroll
      for (int ks = 0; ks < 8; ++ks){
        short8_t b = *reinterpret_cast<const short8_t*>(wb + ks*32);
        acc[g] = __builtin_amdgcn_mfma_f32_16x16x32_bf16(a[ks], b, acc[g], 0, 0, 0);
      }
    }
    #pragma unroll
    for (int r = 0; r < 4; ++r){
      const int m = m0 + mt*16 + lg*4 + r;
      unsigned long long pk =
          (unsigned long long)f2bf(acc[0][r] + bs_g[0])
        | ((unsigned long long)f2bf(acc[1][r] + bs_g[1]) << 16)
        | ((unsigned long long)f2bf(acc[2][r] + bs_g[2]) << 32)
        | ((unsigned long long)f2bf(acc[3][r] + bs_g[3]) << 48);
      *reinterpret_cast<unsigned long long*>(Xp + (size_t)m*1024 + (jw + lr)*4) = pk;
    }
  }
}

// =======================================================================
// Word LSTM v5 (r9-proven, 410 us): 64 blocks x 1024 threads.
// Wave owns 16 j x 4 gates. i+f declared-resident (compiler sinks to
// batched step-top loads -- empirically fastest placement); o-gate in
// 128 KB LDS (XOR-swizzled); g streamed; X prefetched at step start.
// =======================================================================
__global__ __launch_bounds__(1024, 1) void word5_k(
  const unsigned short* __restrict__ Xp,   // [t*1024+seq][j*4+gate] bf16
  const unsigned short* __restrict__ Wb,   // uWhh bf16 [1024][256]
  unsigned short* __restrict__ woutb)      // [seq][t][256] bf16
{
  extern __shared__ char smem[];
  const int tid = threadIdx.x;
  const int w = tid >> 6, l = tid & 63;
  const int lr = l & 15, lg = l >> 4;
  const int S0 = blockIdx.x * 16;
  const int jb = w * 16;
  char* olds = smem + w*8192;              // wave-local o-gate: 16 rows x 512 B
  char* hb0  = smem + 131072;
  char* hb1  = smem + 139264;

  // zero both h buffers (16 KB)
  reinterpret_cast<uint4*>(hb0)[tid] = uint4{0,0,0,0};

  // stage o-gate slice: rows 768 + jb + 0..15
  #pragma unroll
  for (int q = 0; q < 8; ++q){
    const int ck = l*8 + q;
    const int rl = ck >> 5, o16 = ck & 31;
    short8_t v = *reinterpret_cast<const short8_t*>(
        Wb + (size_t)(768 + jb + rl)*256 + o16*8);
    *reinterpret_cast<short8_t*>(olds + rl*512 + ((o16*16) ^ ((rl & 7) << 4))) = v;
  }
  // i,f B-frags (declared resident; allocator places batched loads)
  short8_t wi[8], wf[8];
  #pragma unroll
  for (int ks = 0; ks < 8; ++ks){
    wi[ks] = *reinterpret_cast<const short8_t*>(Wb + (size_t)(      jb + lr)*256 + ks*32 + lg*8);
    wf[ks] = *reinterpret_cast<const short8_t*>(Wb + (size_t)(256 + jb + lr)*256 + ks*32 + lg*8);
  }
  const unsigned short* gbase = Wb + (size_t)(512 + jb + lr)*256 + lg*8;
  float c_reg[4] = {0.f, 0.f, 0.f, 0.f};
  __syncthreads();

  for (int t = 0; t < WLEN; ++t){
    const char* hr = (t & 1) ? hb1 : hb0;
    char* hw = (t & 1) ? hb0 : hb1;
    const unsigned short* pg = gbase;
    asm volatile("" : "+v"(pg));           // re-stream g each step (vs LICM)
    // prefetch X for this step -- hides L2/HBM latency under MFMA chain
    unsigned long long xv[4];
    #pragma unroll
    for (int r = 0; r < 4; ++r)
      xv[r] = *reinterpret_cast<const unsigned long long*>(
          Xp + ((size_t)t*1024 + (S0 + lg*4 + r))*1024 + (jb + lr)*4);
    f32x4 aI = f32x4{0,0,0,0}, aF = f32x4{0,0,0,0};
    f32x4 aG = f32x4{0,0,0,0}, aO = f32x4{0,0,0,0};
    #pragma unroll
    for (int ks = 0; ks < 8; ++ks){
      short8_t a = *reinterpret_cast<const short8_t*>(
          hr + lr*512 + ((ks*64 + lg*16) ^ ((lr & 7) << 4)));
      short8_t bg = *reinterpret_cast<const short8_t*>(pg + ks*32);
      short8_t bo = *reinterpret_cast<const short8_t*>(
          olds + lr*512 + ((ks*64 + lg*16) ^ ((lr & 7) << 4)));
      aI = __builtin_amdgcn_mfma_f32_16x16x32_bf16(a, wi[ks], aI, 0, 0, 0);
      aF = __builtin_amdgcn_mfma_f32_16x16x32_bf16(a, wf[ks], aF, 0, 0, 0);
      aG = __builtin_amdgcn_mfma_f32_16x16x32_bf16(a, bg, aG, 0, 0, 0);
      aO = __builtin_amdgcn_mfma_f32_16x16x32_bf16(a, bo, aO, 0, 0, 0);
    }
    const int j = jb + lr;
    #pragma unroll
    for (int r = 0; r < 4; ++r){
      const int s = lg*4 + r;
      float gi = aI[r] + bf2f((unsigned short)(xv[r]));
      float gf = aF[r] + bf2f((unsigned short)(xv[r] >> 16));
      float gg = aG[r] + bf2f((unsigned short)(xv[r] >> 32));
      float go = aO[r] + bf2f((unsigned short)(xv[r] >> 48));
      float cc = sigf(gf)*c_reg[r] + sigf(gi)*tanhf(gg);
      c_reg[r] = cc;
      float hh = sigf(go)*tanhf(cc);
      unsigned short h16 = f2bf(hh);
      woutb[((size_t)(S0+s)*WLEN + t)*256 + j] = h16;
      *reinterpret_cast<unsigned short*>(hw + s*512 + ((j*2) ^ ((s & 7) << 4))) = h16;
    }
    __syncthreads();
  }
}

// =======================================================================
// conv + sess recurrent LSTM v3 (r9-exact, 413 us proven): 1024 thr,
// one f16 gate-row/thread, k<192 in wr[24], k>=192 in 128 KB LDS.
// blocks 0..7: conv (T=128); 8..39: sess (T=32).
// =======================================================================
__global__ __launch_bounds__(1024) void recur3_k(
  const float* __restrict__ xwc, const f16* __restrict__ w16c, float* __restrict__ convb,
  const float* __restrict__ xws, const f16* __restrict__ w16s, float* __restrict__ soutb)
{
  const float* xw; const f16* w16; float* out; int seq, T;
  if (blockIdx.x < 8){ seq = blockIdx.x;     T = 128; xw = xwc; w16 = w16c; out = convb; }
  else               { seq = blockIdx.x - 8; T = 32;  xw = xws; w16 = w16s; out = soutb; }

  extern __shared__ char smem[];
  uint4* w_lds  = (uint4*)smem;
  float* g_s    = (float*)(smem + 131072);
  f16*   h_half = (f16*)(smem + 131072 + 4096);
  const uint4* h4 = (const uint4*)h_half;

  const int tid = threadIdx.x;
  #pragma unroll
  for (int cth = 0; cth < 8; ++cth)
    w_lds[cth*1024 + tid] = *reinterpret_cast<const uint4*>(w16 + (size_t)tid*256 + 192 + cth*8);
  uint4 wr[24];
  #pragma unroll
  for (int cth = 0; cth < 24; ++cth)
    wr[cth] = *reinterpret_cast<const uint4*>(w16 + (size_t)tid*256 + cth*8);
  if (tid < 32) reinterpret_cast<uint4*>(h_half)[tid] = uint4{0,0,0,0};
  float c_reg = 0.f;
  __syncthreads();

  for (int t = 0; t < T; ++t){
    float acc = xw[(size_t)(seq*T + t)*GATES + tid];
    float a0 = 0.f, a1 = 0.f;
    #pragma unroll
    for (int k = 0; k < 24; k += 2){
      const uint4 h0 = h4[k], h1 = h4[k+1];
      a0 = dot8(wr[k],   h0, a0);
      a1 = dot8(wr[k+1], h1, a1);
    }
    #pragma unroll
    for (int cth = 0; cth < 8; cth += 2){
      const uint4 h0 = h4[24+cth], h1 = h4[25+cth];
      a0 = dot8(w_lds[cth*1024 + tid],     h0, a0);
      a1 = dot8(w_lds[(cth+1)*1024 + tid], h1, a1);
    }
    g_s[tid] = acc + a0 + a1;
    __syncthreads();
    if (tid < HIDN){
      const int j = tid;
      float gi = g_s[j], gf = g_s[HIDN+j], gg = g_s[2*HIDN+j], go = g_s[3*HIDN+j];
      float cc = sigf(gf)*c_reg + sigf(gi)*tanhf(gg);
      c_reg = cc;
      float hh = sigf(go)*tanhf(cc);
      h_half[j] = (f16)hh;
      out[(size_t)(seq*T + t)*HIDN + j] = hh;
    }
    __syncthreads();
  }
}

// =======================================================================
// attention logits via bf16 MFMA + fused tanh/ws2 contraction
// =======================================================================
__global__ __launch_bounds__(256) void attlog_k(
  const unsigned short* __restrict__ woutb, const unsigned short* __restrict__ ws1b,
  const float* __restrict__ ws2, float* __restrict__ logits)
{
  const int tid = threadIdx.x;
  const int w = tid >> 6, l = tid & 63;
  const int lr = l & 15, lg = l >> 4;
  const int m0 = blockIdx.x*64;
  short8_t a[8];
  #pragma unroll
  for (int ks = 0; ks < 8; ++ks){
    const int m = m0 + w*16 + lr;
    a[ks] = *reinterpret_cast<const short8_t*>(woutb + (size_t)m*256 + ks*32 + lg*8);
  }
  float part[4] = {0.f, 0.f, 0.f, 0.f};
  #pragma unroll
  for (int nt = 0; nt < 16; ++nt){
    f32x4 acc = f32x4{0,0,0,0};
    const int n = nt*16 + lr;
    #pragma unroll
    for (int ks = 0; ks < 8; ++ks){
      short8_t b = *reinterpret_cast<const short8_t*>(ws1b + (size_t)n*256 + ks*32 + lg*8);
      acc = __builtin_amdgcn_mfma_f32_16x16x32_bf16(a[ks], b, acc, 0, 0, 0);
    }
    const float w2 = ws2[n];
    #pragma unroll
    for (int r = 0; r < 4; ++r) part[r] += w2 * tanhf(acc[r]);
  }
  #pragma unroll
  for (int r = 0; r < 4; ++r){
    float p = part[r];
    p += __shfl_xor(p, 1, 64);
    p += __shfl_xor(p, 2, 64);
    p += __shfl_xor(p, 4, 64);
    p += __shfl_xor(p, 8, 64);
    if (lr == 0) logits[m0 + w*16 + lg*4 + r] = p;
  }
}

// masked softmax over W + weighted sum -> att fp32 + attb bf16
__global__ __launch_bounds__(256) void att_softmax_k(
  const unsigned short* __restrict__ woutb, const float* __restrict__ logits,
  const int* __restrict__ tok, float* __restrict__ att, unsigned short* __restrict__ attb)
{
  __shared__ float e[WLEN];
  __shared__ float den_s;
  const int n = blockIdx.x, j = threadIdx.x;
  if (j < WLEN){
    float lgt = logits[n*WLEN + j];
    if (tok[n*WLEN + j] == 0) lgt -= 10000.0f;
    e[j] = lgt;
  }
  __syncthreads();
  if (j == 0){
    float mx = -1e30f;
    for (int ww = 0; ww < WLEN; ++ww) mx = fmaxf(mx, e[ww]);
    float den = 0.f;
    for (int ww = 0; ww < WLEN; ++ww){ float ee = expf(e[ww]-mx); e[ww] = ee; den += ee; }
    den_s = den;
  }
  __syncthreads();
  const float inv = 1.0f/den_s;
  float a = 0.f;
  for (int ww = 0; ww < WLEN; ++ww)
    a += e[ww]*bf2f(woutb[((size_t)n*WLEN + ww)*HIDN + j]);
  a *= inv;
  att[(size_t)n*HIDN + j] = a;
  attb[(size_t)n*HIDN + j] = f2bf(a);
}

// =======================================================================
// Fallback word LSTM (fp32, only if workspace too small for X)
// =======================================================================
__global__ __launch_bounds__(256) void word_gates_k(
    const int* __restrict__ tok, const float* __restrict__ emb,
    const float* __restrict__ Wih, const float* __restrict__ Whh,
    const float* __restrict__ bias, const float* __restrict__ hbuf,
    float* __restrict__ G, int t)
{
  __shared__ float As[32][68];
  __shared__ float Bs[32][68];
  const int tid = threadIdx.x;
  const int m0 = blockIdx.x*64, n0 = blockIdx.y*64;
  const int tx = tid & 15, ty = tid >> 4;
  const int lr = tid >> 3;
  const int lc = (tid & 7) * 4;
  float acc[4][4] = {};
  for (int kt = 0; kt < 16; ++kt){
    const int k0 = (kt & 7)*32;
    const bool xp = (kt < 8);
    #pragma unroll
    for (int hf = 0; hf < 2; ++hf){
      const int r = lr + hf*32;
      float4 av, bv;
      if (xp){
        const int token = tok[(m0+r)*WLEN + t];
        av = *reinterpret_cast<const float4*>(emb + (size_t)token*EMBD + k0 + lc);
      } else {
        av = *reinterpret_cast<const float4*>(hbuf + (size_t)(m0+r)*HIDN + k0 + lc);
      }
      const float* bptr = (xp ? Wih : Whh) + (size_t)(n0+r)*HIDN + k0 + lc;
      bv = *reinterpret_cast<const float4*>(bptr);
      As[lc+0][r]=av.x; As[lc+1][r]=av.y; As[lc+2][r]=av.z; As[lc+3][r]=av.w;
      Bs[lc+0][r]=bv.x; Bs[lc+1][r]=bv.y; Bs[lc+2][r]=bv.z; Bs[lc+3][r]=bv.w;
    }
    __syncthreads();
    #pragma unroll
    for (int kk = 0; kk < 32; ++kk){
      const float4 a = *reinterpret_cast<const float4*>(&As[kk][ty*4]);
      const float4 b = *reinterpret_cast<const float4*>(&Bs[kk][tx*4]);
      acc[0][0] += a.x*b.x; acc[0][1] += a.x*b.y; acc[0][2] += a.x*b.z; acc[0][3] += a.x*b.w;
      acc[1][0] += a.y*b.x; acc[1][1] += a.y*b.y; acc[1][2] += a.y*b.z; acc[1][3] += a.y*b.w;
      acc[2][0] += a.z*b.x; acc[2][1] += a.z*b.y; acc[2][2] += a.z*b.z; acc[2][3] += a.z*b.w;
      acc[3][0] += a.w*b.x; acc[3][1] += a.w*b.y; acc[3][2] += a.w*b.z; acc[3][3] += a.w*b.w;
    }
    __syncthreads();
  }
  const float4 bb = *reinterpret_cast<const float4*>(bias + n0 + tx*4);
  #pragma unroll
  for (int i = 0; i < 4; ++i){
    float4 o;
    o.x = acc[i][0]+bb.x; o.y = acc[i][1]+bb.y; o.z = acc[i][2]+bb.z; o.w = acc[i][3]+bb.w;
    *reinterpret_cast<float4*>(G + (size_t)(m0+ty*4+i)*GATES + n0 + tx*4) = o;
  }
}

__global__ __launch_bounds__(256) void word_update_k(
  const float* __restrict__ G, float* __restrict__ h, float* __restrict__ c,
  unsigned short* __restrict__ woutb, int t)
{
  int idx = blockIdx.x*256 + threadIdx.x;
  int m = idx >> 8, j = idx & 255;
  const float* g = G + (size_t)m*GATES;
  float gi = g[j], gf = g[HIDN+j], gg = g[2*HIDN+j], go = g[3*HIDN+j];
  float cc = c[idx];
  cc = sigf(gf)*cc + sigf(gi)*tanhf(gg);
  float hh = sigf(go)*tanhf(cc);
  c[idx] = cc; h[idx] = hh;
  woutb[(size_t)m*WLEN*HIDN + (size_t)t*HIDN + j] = f2bf(hh);
}

// =======================================================================
// Parallel state "scan" prep
// =======================================================================
__global__ __launch_bounds__(256) void scan_prep_k(
  const float* __restrict__ sess_out, const float* __restrict__ conv_out,
  const int* __restrict__ stm, float* __restrict__ state, float* __restrict__ onec)
{
  const int bl = blockIdx.x;
  const int b = bl >> 7, l = bl & 127;
  const int j = threadIdx.x;
  float ones = 0.f;
  #pragma unroll
  for (int s = 1; s < SNUM; ++s){
    const int sv = stm[(size_t)bl*SNUM + s];
    float vg = 0.f;
    if (sv > 0){
      int p = sv - 1; if (p > PLEN-1) p = PLEN-1;
      vg = sess_out[((size_t)(b*4 + (s-1))*PLEN + p)*HIDN + j];
    }
    float v = vg;
    if (sv == -1){
      v = 0.f;
      if (l > 0){
        const int pv = stm[(size_t)(bl-1)*SNUM + s];
        if (pv > 0){
          int p2 = pv - 1; if (p2 > PLEN-1) p2 = PLEN-1;
          v = sess_out[((size_t)(b*4 + (s-1))*PLEN + p2)*HIDN + j];
        }
      }
    }
    if (sv != 0) ones += v;
    state[((size_t)bl*SNUM + s)*HIDN + j] = vg;
  }
  onec[(size_t)bl*(2*HIDN) + j] = ones * 0.25f;
  const int lp = (l == 0) ? 0 : (l-1);
  onec[(size_t)bl*(2*HIDN) + HIDN + j] = conv_out[((size_t)(b*LLEN + lp))*HIDN + j];
}

// =======================================================================
// final scores + log_softmax
// =======================================================================
__global__ __launch_bounds__(256) void scores_k(
  const float* __restrict__ state, const float* __restrict__ up, float* __restrict__ out)
{
  const int n = blockIdx.x, j = threadIdx.x;
  __shared__ float red[SNUM][4];
  const float u = up[(size_t)n*HIDN + j];
  const int lane = j & 63, wid = j >> 6;
  #pragma unroll
  for (int s = 0; s < SNUM; ++s){
    float p = state[((size_t)n*SNUM + s)*HIDN + j]*u;
    for (int off = 32; off; off >>= 1) p += __shfl_down(p, off, 64);
    if (lane == 0) red[s][wid] = p;
  }
  __syncthreads();
  if (j == 0){
    float sc[SNUM]; float mx = -1e30f;
    #pragma unroll
    for (int s = 0; s < SNUM; ++s){
      sc[s] = red[s][0]+red[s][1]+red[s][2]+red[s][3];
      mx = fmaxf(mx, sc[s]);
    }
    float den = 0.f;
    #pragma unroll
    for (int s = 0; s < SNUM; ++s) den += expf(sc[s]-mx);
    const float ls = logf(den);
    #pragma unroll
    for (int s = 0; s < SNUM; ++s) out[(size_t)n*SNUM + s] = sc[s]-mx-ls;
  }
}

// ---------------- workspace layout (float offsets) ----------------
static const size_t OFF_G     = 0;                        // fallback
static const size_t OFF_H     = OFF_G     + 1048576;
static const size_t OFF_C     = OFF_H     + 262144;
static const size_t OFF_ATT   = OFF_C     + 262144;
static const size_t OFF_ATTB  = OFF_ATT   + 262144;       // bf16 att
static const size_t OFF_XWC   = OFF_ATTB  + 131072;
static const size_t OFF_XWS   = OFF_XWC   + 1048576;
static const size_t OFF_CONV  = OFF_XWS   + 1048576;
static const size_t OFF_SOUT  = OFF_CONV  + 262144;
static const size_t OFF_STATE = OFF_SOUT  + 262144;
static const size_t OFF_ONEC  = OFF_STATE + 1310720;
static const size_t OFF_UP    = OFF_ONEC  + 524288;
static const size_t OFF_LOG   = OFF_UP    + 262144;
static const size_t OFF_UWHHB = OFF_LOG   + 49152;        // bf16 uWhh
static const size_t OFF_WIHB  = OFF_UWHHB + 131072;       // bf16 uWih
static const size_t OFF_WS1B  = OFF_WIHB  + 131072;       // bf16 ws1
static const size_t OFF_CWIHB = OFF_WS1B  + 32768;        // bf16 cWih
static const size_t OFF_SWIHB = OFF_CWIHB + 131072;       // bf16 sWih
static const size_t OFF_W16C  = OFF_SWIHB + 131072;       // f16 cWhh
static const size_t OFF_W16S  = OFF_W16C  + 131072;       // f16 sWhh
static const size_t OFF_WOUTB = OFF_W16S  + 131072;       // bf16 wout
static const size_t OFF_X     = OFF_WOUTB + 6291456;      // bf16 X (gate-interleaved)
static const size_t NEED_X_FLOATS = OFF_X + (size_t)49152*512;

static const size_t WORD_LDS_BYTES  = 131072 + 16384;         // 147456
static const size_t RECUR_LDS_BYTES = 131072 + 4096 + 512;    // 135680

extern "C" void kernel_launch(void* const* d_in, const int* in_sizes, int n_in,
                              void* d_out, int out_size, void* d_ws, size_t ws_size,
                              hipStream_t stream)
{
  const int*   tok   = (const int*)  d_in[0];
  const int*   perm  = (const int*)  d_in[2];
  const int*   stm   = (const int*)  d_in[3];
  const float* emb   = (const float*)d_in[5];
  const float* uWih  = (const float*)d_in[6];
  const float* uWhh  = (const float*)d_in[7];
  const float* ub    = (const float*)d_in[8];
  const float* ws1   = (const float*)d_in[9];
  const float* ws2   = (const float*)d_in[10];
  const float* cWih  = (const float*)d_in[11];
  const float* cWhh  = (const float*)d_in[12];
  const float* cb    = (const float*)d_in[13];
  const float* sWih  = (const float*)d_in[14];
  const float* sWhh  = (const float*)d_in[15];
  const float* sb    = (const float*)d_in[16];
  const float* Wp    = (const float*)d_in[17];
  const float* bp    = (const float*)d_in[18];
  const float* Ws    = (const float*)d_in[19];
  const float* bs    = (const float*)d_in[20];

  float* wsf    = (float*)d_ws;
  float* G      = wsf + OFF_G;
  float* h      = wsf + OFF_H;
  float* c      = wsf + OFF_C;
  float* att    = wsf + OFF_ATT;
  float* xwc    = wsf + OFF_XWC;
  float* xws    = wsf + OFF_XWS;
  float* convb  = wsf + OFF_CONV;
  float* soutb  = wsf + OFF_SOUT;
  float* statem = wsf + OFF_STATE;
  float* onec   = wsf + OFF_ONEC;
  float* upb    = wsf + OFF_UP;
  float* logits = wsf + OFF_LOG;
  unsigned short* attb  = (unsigned short*)(wsf + OFF_ATTB);
  unsigned short* uwhhb = (unsigned short*)(wsf + OFF_UWHHB);
  unsigned short* wihb  = (unsigned short*)(wsf + OFF_WIHB);
  unsigned short* ws1b  = (unsigned short*)(wsf + OFF_WS1B);
  unsigned short* cwihb = (unsigned short*)(wsf + OFF_CWIHB);
  unsigned short* swihb = (unsigned short*)(wsf + OFF_SWIHB);
  f16*   w16c   = (f16*)(wsf + OFF_W16C);
  f16*   w16s   = (f16*)(wsf + OFF_W16S);
  unsigned short* woutb = (unsigned short*)(wsf + OFF_WOUTB);
  unsigned short* X16   = (unsigned short*)(wsf + OFF_X);

  const bool useX = ws_size >= NEED_X_FLOATS*sizeof(float);

  hipFuncSetAttribute(reinterpret_cast<const void*>(word5_k),
                      hipFuncAttributeMaxDynamicSharedMemorySize, (int)WORD_LDS_BYTES);
  hipFuncSetAttribute(reinterpret_cast<const void*>(recur3_k),
                      hipFuncAttributeMaxDynamicSharedMemorySize, (int)RECUR_LDS_BYTES);

  // weight conversions
  cvt2_k<<<256, 256, 0, stream>>>(uWhh, uWih, uwhhb, wihb, 262144);
  cvt2_k<<<256, 256, 0, stream>>>(cWih, sWih, cwihb, swihb, 262144);
  cvt_w16_k<<<1024, 256, 0, stream>>>(cWhh, sWhh, w16c, w16s);
  cvt1_k<<<64, 256, 0, stream>>>(ws1, ws1b, 65536);

  // ---- word LSTM ----
  if (useX){
    xgemm4_k<<<dim3(768,4), 256, 0, stream>>>(emb, wihb, ub, tok, X16);
    word5_k<<<64, 1024, WORD_LDS_BYTES, stream>>>(X16, uwhhb, woutb);
  } else {
    hipMemsetAsync(h, 0, 2*262144*sizeof(float), stream);
    for (int t = 0; t < WLEN; ++t){
      word_gates_k<<<dim3(16,16), 256, 0, stream>>>(tok, emb, uWih, uWhh, ub, h, G, t);
      word_update_k<<<1024, 256, 0, stream>>>(G, h, c, woutb, t);
    }
  }

  // ---- attention ----
  attlog_k<<<768, 256, 0, stream>>>(woutb, ws1b, ws2, logits);
  att_softmax_k<<<1024, 256, 0, stream>>>(woutb, logits, tok, att, attb);

  // ---- x-parts of conv/session LSTMs (bf16 MFMA, bias folded) ----
  mmabt_k<2><<<dim3(16,16), 256, 0, stream>>>(attb, cwihb, cb, nullptr, xwc);
  mmabt_k<1><<<dim3(16,16), 256, 0, stream>>>(attb, swihb, sb, perm, xws);

  // ---- conv + sess recurrent LSTMs (r9-proven config) ----
  recur3_k<<<40, 1024, RECUR_LDS_BYTES, stream>>>(xwc, w16c, convb, xws, w16s, soutb);

  // ---- parallel state "scan" ----
  scan_prep_k<<<1024, 256, 0, stream>>>(soutb, convb, stm, statem, onec);
  gemm_abt64_k<false,true,true,false><<<dim3(16,4), 256, 0, stream>>>(
    onec, nullptr, Wp, bp, statem, nullptr, 512, HIDN, SNUM*HIDN);

  // ---- final projection + scores + log_softmax ----
  gemm_abt64_k<false,true,true,true><<<dim3(16,4), 256, 0, stream>>>(
    att, convb, Ws, bs, upb, nullptr, 512, HIDN, HIDN);
  scores_k<<<1024, 256, 0, stream>>>(statem, upb, (float*)d_out);
}